// Round 4
// baseline (7696.484 us; speedup 1.0000x reference)
//
#include <hip/hip_runtime.h>
#include <hip/hip_bf16.h>
#include <math.h>

#define BB   512
#define NIN  128
#define DIMD 512
#define QKD  128
#define GSZ  32
#define GRP  4
#define HID  1024
#define HID2 2048
#define ROT  32
#define NLAYER 2
#define EPSF 1e-5f
#define BINS 100

// ---------------- embedding: h[b,n,:] = emb[n, tok[b,n], :] + pos[n,:] ----------------
__global__ void k_embed(const int* __restrict__ tokens, const float* __restrict__ emb,
                        const float* __restrict__ pos, float* __restrict__ h) {
    int bn = blockIdx.x;              // b*NIN + n
    int n  = bn % NIN;
    int tok = tokens[bn];
    const float4* e4 = (const float4*)(emb + ((size_t)n * BINS + tok) * DIMD);
    const float4* p4 = (const float4*)(pos + (size_t)n * DIMD);
    float4* h4 = (float4*)(h + (size_t)bn * DIMD);
    int t = threadIdx.x;              // 128 threads, 128 float4 per row
    float4 a = e4[t], b = p4[t];
    h4[t] = make_float4(a.x + b.x, a.y + b.y, a.z + b.z, a.w + b.w);
}

// ---------------- RMS scale per row: scale = ng / max(||h||/sqrt(DIM), eps) ----------------
__global__ void k_rms(const float* __restrict__ h, float* __restrict__ scale,
                      const float* __restrict__ ngp) {
    int row  = blockIdx.x * 4 + (threadIdx.x >> 6);
    int lane = threadIdx.x & 63;
    const float4* r4 = (const float4*)(h + (size_t)row * DIMD);
    float s = 0.f;
    #pragma unroll
    for (int i = 0; i < 2; ++i) {
        float4 v = r4[lane + 64 * i];
        s += v.x * v.x + v.y * v.y + v.z * v.z + v.w * v.w;
    }
    #pragma unroll
    for (int o = 32; o; o >>= 1) s += __shfl_down(s, o);
    if (lane == 0) {
        float nrm = sqrtf(s) * (1.0f / sqrtf((float)DIMD));
        scale[row] = ngp[0] / fmaxf(nrm, EPSF);
    }
}

// ---------------- build nx: first half = shifted(n-1) scaled, second half = own scaled ----------------
// h/scale/nx are chunk-local pointers; chunk starts at a batch boundary so (local row % NIN) == n.
__global__ void k_nx(const float* __restrict__ h, const float* __restrict__ scale,
                     float* __restrict__ nx) {
    int bn = blockIdx.x; int n = bn % NIN;
    int t = threadIdx.x;   // 128 float4
    float4* o4 = (float4*)(nx + (size_t)bn * DIMD);
    if (t < 64) {
        if (n == 0) { o4[t] = make_float4(0.f, 0.f, 0.f, 0.f); return; }
        float sc = scale[bn - 1];
        float4 v = ((const float4*)(h + (size_t)(bn - 1) * DIMD))[t];
        o4[t] = make_float4(v.x * sc, v.y * sc, v.z * sc, v.w * sc);
    } else {
        float sc = scale[bn];
        float4 v = ((const float4*)(h + (size_t)bn * DIMD))[t];
        o4[t] = make_float4(v.x * sc, v.y * sc, v.z * sc, v.w * sc);
    }
}

// ---------------- fp32 tiled GEMM: C = act(A@W + bias) [+ resid] ----------------
// A: M x K row-major, W: K x N row-major. 64x64 tile, BK=16, 256 threads, 4x4 micro-tile.
template<int ACT>   // 0: none, 1: silu
__global__ __launch_bounds__(256) void k_gemm(const float* __restrict__ A,
        const float* __restrict__ W, const float* __restrict__ bias,
        const float* __restrict__ resid, float* __restrict__ C,
        int M, int N, int K) {
    __shared__ float As[16][68];   // [k][m]
    __shared__ float Bs[16][68];   // [k][n]
    int tid = threadIdx.x;
    int bm = blockIdx.y * 64, bn = blockIdx.x * 64;
    int tr = (tid / 16) * 4;
    int tc = (tid % 16) * 4;
    int larow = tid / 4,  lacol = (tid % 4) * 4;
    int lbrow = tid / 16, lbcol = (tid % 16) * 4;
    float acc[4][4] = {};
    for (int k0 = 0; k0 < K; k0 += 16) {
        float4 av = *(const float4*)(A + (size_t)(bm + larow) * K + k0 + lacol);
        float4 bv = *(const float4*)(W + (size_t)(k0 + lbrow) * N + bn + lbcol);
        __syncthreads();
        As[lacol + 0][larow] = av.x; As[lacol + 1][larow] = av.y;
        As[lacol + 2][larow] = av.z; As[lacol + 3][larow] = av.w;
        *(float4*)&Bs[lbrow][lbcol] = bv;
        __syncthreads();
        #pragma unroll
        for (int kk = 0; kk < 16; ++kk) {
            float a0 = As[kk][tr], a1 = As[kk][tr+1], a2 = As[kk][tr+2], a3 = As[kk][tr+3];
            float b0 = Bs[kk][tc], b1 = Bs[kk][tc+1], b2 = Bs[kk][tc+2], b3 = Bs[kk][tc+3];
            acc[0][0] += a0*b0; acc[0][1] += a0*b1; acc[0][2] += a0*b2; acc[0][3] += a0*b3;
            acc[1][0] += a1*b0; acc[1][1] += a1*b1; acc[1][2] += a1*b2; acc[1][3] += a1*b3;
            acc[2][0] += a2*b0; acc[2][1] += a2*b1; acc[2][2] += a2*b2; acc[2][3] += a2*b3;
            acc[3][0] += a3*b0; acc[3][1] += a3*b1; acc[3][2] += a3*b2; acc[3][3] += a3*b3;
        }
    }
    #pragma unroll
    for (int i = 0; i < 4; ++i) {
        size_t row = bm + tr + i;
        #pragma unroll
        for (int j = 0; j < 4; ++j) {
            int col = bn + tc + j;
            float v = acc[i][j] + bias[col];
            if (ACT == 1) v = v / (1.0f + expf(-v));   // silu
            if (resid) v += resid[row * N + col];
            C[row * N + col] = v;
        }
    }
}

// ---------------- rotary cos/sin tables (NIN x 16 each) ----------------
__global__ void k_cossin(float* __restrict__ cosb, float* __restrict__ sinb) {
    int idx = blockIdx.x * 256 + threadIdx.x;
    if (idx >= NIN * 16) return;
    int n = idx / 16, i = idx % 16;
    double inv = pow(10000.0, -(double)(2 * i) / (double)ROT);
    double f = (double)n * inv;
    cosb[idx] = (float)cos(f);
    sinb[idx] = (float)sin(f);
}

// ---------------- qs = qk*gamma+beta (4 heads), apply rotary to first 32 dims ----------------
__global__ void k_rot(const float* __restrict__ qk, const float* __restrict__ gm,
                      const float* __restrict__ bt, const float* __restrict__ cosb,
                      const float* __restrict__ sinb, float* __restrict__ q4) {
    int bn = blockIdx.x; int n = bn % NIN;
    int d = threadIdx.x;   // 128
    float x = qk[(size_t)bn * QKD + d];
    float xp0 = 0.f;
    int dp = d ^ 1;
    if (d < ROT) xp0 = qk[(size_t)bn * QKD + dp];
    #pragma unroll
    for (int c = 0; c < 4; ++c) {
        float val = x * gm[c * QKD + d] + bt[c * QKD + d];
        float outv;
        if (d < ROT) {
            int i = d >> 1;
            float cs = cosb[n * 16 + i], sn = sinb[n * 16 + i];
            float xp = xp0 * gm[c * QKD + dp] + bt[c * QKD + dp];
            outv = ((d & 1) == 0) ? (val * cs - xp * sn) : (val * cs + xp * sn);
        } else outv = val;
        q4[((size_t)bn * 4 + c) * QKD + d] = outv;
    }
}

// ---------------- fused grouped attention (quad relu^2 causal + linear prev-group cumsum), gated ----------------
// grid: (HID/256, GRP, CB); 256 threads; each thread owns one output column e, 32 rows.
__global__ __launch_bounds__(256) void k_attn(const float* __restrict__ q4,
        const float* __restrict__ hid, const float* __restrict__ rp,
        float* __restrict__ attn_out) {
    int et = blockIdx.x, g = blockIdx.y, b = blockIdx.z;
    int tid = threadIdx.x;
    __shared__ float Qq[32][QKD + 4], Lq[32][QKD + 4], Kt[32][QKD + 4];
    __shared__ float S[32][32];
    __shared__ float rps[GSZ];
    if (tid < GSZ) rps[tid] = rp[tid] * sqrtf((float)QKD);
    size_t base = (size_t)b * NIN + (size_t)g * GSZ;
    for (int it = tid; it < 32 * 32; it += 256) {   // 32 rows x 32 float4
        int i = it / 32, f4 = it % 32;
        ((float4*)Qq[i])[f4] = ((const float4*)(q4 + ((base + i) * 4 + 0) * QKD))[f4];
        ((float4*)Lq[i])[f4] = ((const float4*)(q4 + ((base + i) * 4 + 1) * QKD))[f4];
    }
    float acc[32];
    #pragma unroll
    for (int i = 0; i < 32; ++i) acc[i] = 0.f;
    int e = et * 256 + tid;
    for (int gp = 0; gp <= g; ++gp) {
        bool quad = (gp == g);
        size_t kbase = (size_t)b * NIN + (size_t)gp * GSZ;
        int c = quad ? 2 : 3;
        __syncthreads();
        for (int it = tid; it < 32 * 32; it += 256) {
            int i = it / 32, f4 = it % 32;
            ((float4*)Kt[i])[f4] = ((const float4*)(q4 + ((kbase + i) * 4 + c) * QKD))[f4];
        }
        __syncthreads();
        for (int it = tid; it < 1024; it += 256) {
            int i = it / 32, j = it % 32;
            const float* Qrow = quad ? Qq[i] : Lq[i];
            float s = 0.f;
            #pragma unroll
            for (int d = 0; d < QKD; d += 4) {
                float4 qv = *(const float4*)&Qrow[d];
                float4 kv = *(const float4*)&Kt[j][d];
                s += qv.x * kv.x + qv.y * kv.y + qv.z * kv.z + qv.w * kv.w;
            }
            s *= (1.0f / GSZ);
            if (quad) {
                int neg = i - j;
                if (j > i) s = 0.f;
                else {
                    int bucket;
                    if (neg < 16) bucket = neg;
                    else {
                        bucket = 16 + (int)(logf((float)neg * (1.0f / 16.0f)) * (16.0f / logf(8.0f)));
                        if (bucket > 31) bucket = 31;
                    }
                    s += rps[bucket];
                    s = fmaxf(s, 0.f);
                    s = s * s;
                }
            }
            S[i][j] = s;
        }
        __syncthreads();
        const float* vcol = hid + kbase * HID2 + e;
        #pragma unroll 4
        for (int j = 0; j < 32; ++j) {
            float vv = vcol[(size_t)j * HID2];
            #pragma unroll
            for (int i = 0; i < 32; ++i) acc[i] += S[i][j] * vv;
        }
    }
    #pragma unroll
    for (int i = 0; i < 32; ++i) {
        size_t row = base + i;
        float gate = hid[row * HID2 + HID + e];
        attn_out[row * HID + e] = gate * acc[i];
    }
}

// ---------------- final LayerNorm ----------------
__global__ void k_ln(const float* __restrict__ h, const float* __restrict__ lng,
                     const float* __restrict__ lnb, float* __restrict__ out) {
    int bn = blockIdx.x;
    int t = threadIdx.x;   // 128
    const float4* r4 = (const float4*)(h + (size_t)bn * DIMD);
    float4 v = r4[t];
    float s  = v.x + v.y + v.z + v.w;
    float sq = v.x * v.x + v.y * v.y + v.z * v.z + v.w * v.w;
    __shared__ float red[4];
    #pragma unroll
    for (int o = 32; o; o >>= 1) { s += __shfl_down(s, o); sq += __shfl_down(sq, o); }
    int lane = t & 63, w = t >> 6;
    if (lane == 0) { red[w] = s; red[2 + w] = sq; }
    __syncthreads();
    float mu  = (red[0] + red[1]) * (1.0f / DIMD);
    float var = (red[2] + red[3]) * (1.0f / DIMD) - mu * mu;
    float rstd = 1.0f / sqrtf(var + EPSF);
    float4 gg = ((const float4*)lng)[t];
    float4 bb = ((const float4*)lnb)[t];
    float4 o;
    o.x = (v.x - mu) * rstd * gg.x + bb.x;
    o.y = (v.y - mu) * rstd * gg.y + bb.y;
    o.z = (v.z - mu) * rstd * gg.z + bb.z;
    o.w = (v.w - mu) * rstd * gg.w + bb.w;
    ((float4*)(out + (size_t)bn * DIMD))[t] = o;
}

extern "C" void kernel_launch(void* const* d_in, const int* in_sizes, int n_in,
                              void* d_out, int out_size, void* d_ws, size_t ws_size,
                              hipStream_t stream) {
    const int*   tokens = (const int*)d_in[0];
    const float* emb    = (const float*)d_in[1];
    const float* pos    = (const float*)d_in[2];
    const float* norm_g = (const float*)d_in[3];
    const float* Wh     = (const float*)d_in[4];
    const float* bh     = (const float*)d_in[5];
    const float* Wqk    = (const float*)d_in[6];
    const float* bqk    = (const float*)d_in[7];
    const float* gamma  = (const float*)d_in[8];
    const float* beta   = (const float*)d_in[9];
    const float* rp     = (const float*)d_in[10];
    const float* Wout   = (const float*)d_in[11];
    const float* bout   = (const float*)d_in[12];
    const float* lng    = (const float*)d_in[13];
    const float* lnb    = (const float*)d_in[14];

    float* h = (float*)d_out;                 // hidden state lives in d_out
    float* ws = (float*)d_ws;

    // ---- size the batch chunk from ws_size (never exceed workspace) ----
    const size_t wsFloats   = ws_size / sizeof(float);
    const size_t fixedFloats = (size_t)BB * NIN + 2 * NIN * 16 + 64; // scale + cos/sin + pad
    const size_t perBatch   = (size_t)NIN * (DIMD + HID2 + QKD + HID); // nx+hid+qk+attn per batch
    int CB = BB;
    while (CB > 1 && fixedFloats + (size_t)CB * perBatch > wsFloats) CB >>= 1;

    size_t off = 0;
    float* scale = ws + off; off += (size_t)BB * NIN;
    float* cosb  = ws + off; off += NIN * 16;
    float* sinb  = ws + off; off += NIN * 16;
    off = (off + 63) & ~(size_t)63;
    float* nx    = ws + off; off += (size_t)CB * NIN * DIMD;    // also reused as q4
    float* hid   = ws + off; off += (size_t)CB * NIN * HID2;
    float* qk    = ws + off; off += (size_t)CB * NIN * QKD;
    float* attn  = ws + off; off += (size_t)CB * NIN * HID;
    float* q4 = nx;   // alias: nx dead after the two GEMMs, q4 same size

    const int BN_ = BB * NIN;

    k_cossin<<<8, 256, 0, stream>>>(cosb, sinb);
    k_embed<<<BN_, 128, 0, stream>>>(tokens, emb, pos, h);

    for (int l = 0; l < NLAYER; ++l) {
        const float* Wh_l  = Wh   + (size_t)l * DIMD * HID2;
        const float* bh_l  = bh   + (size_t)l * HID2;
        const float* Wqk_l = Wqk  + (size_t)l * DIMD * QKD;
        const float* bqk_l = bqk  + (size_t)l * QKD;
        const float* gm_l  = gamma+ (size_t)l * 4 * QKD;
        const float* bt_l  = beta + (size_t)l * 4 * QKD;
        const float* rp_l  = rp   + (size_t)l * 32;
        const float* Wo_l  = Wout + (size_t)l * HID * DIMD;
        const float* bo_l  = bout + (size_t)l * DIMD;

        for (int c0 = 0; c0 < BB; c0 += CB) {
            const int rowsC = CB * NIN;
            float* h_c = h + (size_t)c0 * NIN * DIMD;

            k_rms<<<rowsC / 4, 256, 0, stream>>>(h_c, scale, norm_g + l);
            k_nx<<<rowsC, 128, 0, stream>>>(h_c, scale, nx);

            dim3 g1(HID2 / 64, rowsC / 64);
            k_gemm<1><<<g1, 256, 0, stream>>>(nx, Wh_l, bh_l, nullptr, hid, rowsC, HID2, DIMD);
            dim3 g2(QKD / 64, rowsC / 64);
            k_gemm<1><<<g2, 256, 0, stream>>>(nx, Wqk_l, bqk_l, nullptr, qk, rowsC, QKD, DIMD);

            k_rot<<<rowsC, 128, 0, stream>>>(qk, gm_l, bt_l, cosb, sinb, q4);

            dim3 ga(HID / 256, GRP, CB);
            k_attn<<<ga, 256, 0, stream>>>(q4, hid, rp_l, attn);

            dim3 g3(DIMD / 64, rowsC / 64);
            k_gemm<0><<<g3, 256, 0, stream>>>(attn, Wo_l, bo_l, h_c, h_c, rowsC, DIMD, HID);
        }
    }

    k_ln<<<BN_, 128, 0, stream>>>(h, lng, lnb, (float*)d_out);
}

// Round 5
// 3024.738 us; speedup vs baseline: 2.5445x; 2.5445x over previous
//
#include <hip/hip_runtime.h>
#include <hip/hip_bf16.h>
#include <math.h>
#include <stdint.h>

#define BB   512
#define NIN  128
#define DIMD 512
#define QKD  128
#define GSZ  32
#define GRP  4
#define HID  1024
#define HID2 2048
#define ROT  32
#define NLAYER 2
#define EPSF 1e-5f
#define BINS 100

typedef __bf16 bf16x8 __attribute__((ext_vector_type(8)));
typedef float  f32x4  __attribute__((ext_vector_type(4)));

__device__ __forceinline__ unsigned short f2bf(float f) {
    union { float f; uint32_t u; } v; v.f = f;
    return (unsigned short)((v.u + 0x7FFFu + ((v.u >> 16) & 1u)) >> 16);
}

// ---------------- embedding ----------------
__global__ void k_embed(const int* __restrict__ tokens, const float* __restrict__ emb,
                        const float* __restrict__ pos, float* __restrict__ h) {
    int bn = blockIdx.x;
    int n  = bn % NIN;
    int tok = tokens[bn];
    const float4* e4 = (const float4*)(emb + ((size_t)n * BINS + tok) * DIMD);
    const float4* p4 = (const float4*)(pos + (size_t)n * DIMD);
    float4* h4 = (float4*)(h + (size_t)bn * DIMD);
    int t = threadIdx.x;
    float4 a = e4[t], b = p4[t];
    h4[t] = make_float4(a.x + b.x, a.y + b.y, a.z + b.z, a.w + b.w);
}

// ---------------- RMS scale ----------------
__global__ void k_rms(const float* __restrict__ h, float* __restrict__ scale,
                      const float* __restrict__ ngp) {
    int row  = blockIdx.x * 4 + (threadIdx.x >> 6);
    int lane = threadIdx.x & 63;
    const float4* r4 = (const float4*)(h + (size_t)row * DIMD);
    float s = 0.f;
    #pragma unroll
    for (int i = 0; i < 2; ++i) {
        float4 v = r4[lane + 64 * i];
        s += v.x * v.x + v.y * v.y + v.z * v.z + v.w * v.w;
    }
    #pragma unroll
    for (int o = 32; o; o >>= 1) s += __shfl_down(s, o);
    if (lane == 0) {
        float nrm = sqrtf(s) * (1.0f / sqrtf((float)DIMD));
        scale[row] = ngp[0] / fmaxf(nrm, EPSF);
    }
}

// ---------------- build nx in bf16 (half-shifted) ----------------
__global__ void k_nx(const float* __restrict__ h, const float* __restrict__ scale,
                     unsigned short* __restrict__ nx) {
    int bn = blockIdx.x; int n = bn % NIN;
    int t = threadIdx.x;   // 128 threads x 4 elems
    ushort4* o4 = (ushort4*)(nx + (size_t)bn * DIMD) + 0;
    float4 v; float sc;
    if (t < 64) {
        if (n == 0) {
            ushort z = f2bf(0.f);
            ((ushort4*)(nx + (size_t)bn * DIMD))[t] = make_ushort4(z, z, z, z);
            return;
        }
        sc = scale[bn - 1];
        v = ((const float4*)(h + (size_t)(bn - 1) * DIMD))[t];
    } else {
        sc = scale[bn];
        v = ((const float4*)(h + (size_t)bn * DIMD))[t];
    }
    ushort4 o = make_ushort4(f2bf(v.x * sc), f2bf(v.y * sc), f2bf(v.z * sc), f2bf(v.w * sc));
    ((ushort4*)(nx + (size_t)bn * DIMD))[t] = o;
}

// ---------------- weight cast+transpose: Wt[n][k] = bf16(W[k][n]) ----------------
__global__ void k_wcast(const float* __restrict__ W, unsigned short* __restrict__ Wt,
                        int K, int N) {
    int idx = blockIdx.x * 256 + threadIdx.x;
    int total = N * (K / 8);
    if (idx >= total) return;
    int kb = idx / N, n = idx % N;
    #pragma unroll
    for (int j = 0; j < 8; ++j)
        Wt[(size_t)n * K + kb * 8 + j] = f2bf(W[(size_t)(kb * 8 + j) * N + n]);
}

// ---------------- bf16 MFMA GEMM: C = act(A@Bt^T + bias) [+resid], fp32 out ----------------
// A: M x K bf16 row-major. Bt: N x K bf16 row-major (pre-transposed weight).
// 128x128 tile, BK=32, 256 threads (4 waves, each 64x64), 16x16x32 MFMA.
#define GLOAD_LDS(gp, lp) __builtin_amdgcn_global_load_lds( \
    (const __attribute__((address_space(1))) uint32_t*)(gp), \
    (__attribute__((address_space(3))) uint32_t*)(lp), 16, 0, 0)

template<int ACT, int RESID>
__global__ __launch_bounds__(256) void k_gemm_bf16(
        const unsigned short* __restrict__ A,
        const unsigned short* __restrict__ Bt,
        const float* __restrict__ bias,
        const float* __restrict__ resid,
        float* __restrict__ C,
        int M, int N, int K) {
    __shared__ unsigned short As[128 * 32];
    __shared__ unsigned short Bs[128 * 32];
    const int tid  = threadIdx.x;
    const int bm   = blockIdx.y * 128, bn = blockIdx.x * 128;
    const int lane = tid & 63, wave = tid >> 6;
    const int wm = (wave >> 1) * 64, wn = (wave & 1) * 64;
    const int l15 = lane & 15, l4 = lane >> 4;

    f32x4 acc[4][4];
    #pragma unroll
    for (int i = 0; i < 4; ++i)
        #pragma unroll
        for (int j = 0; j < 4; ++j) acc[i][j] = (f32x4){0.f, 0.f, 0.f, 0.f};

    const int rowA = tid >> 2;              // 0..63
    const int colB = (tid & 3) * 16;        // byte offset in 64B row
    const char* gA = (const char*)(A  + (size_t)(bm + rowA) * K) + colB;
    const char* gB = (const char*)(Bt + (size_t)(bn + rowA) * K) + colB;
    const size_t stride64 = (size_t)64 * K * 2;   // 64 rows in bytes
    unsigned short* ldsA = As + tid * 8;          // tid*16 bytes
    unsigned short* ldsB = Bs + tid * 8;

    for (int k0 = 0; k0 < K; k0 += 32) {
        GLOAD_LDS(gA + (size_t)k0 * 2,            ldsA);
        GLOAD_LDS(gA + (size_t)k0 * 2 + stride64, ldsA + 2048);
        GLOAD_LDS(gB + (size_t)k0 * 2,            ldsB);
        GLOAD_LDS(gB + (size_t)k0 * 2 + stride64, ldsB + 2048);
        asm volatile("s_waitcnt vmcnt(0)" ::: "memory");
        __syncthreads();

        bf16x8 af[4], bfr[4];
        #pragma unroll
        for (int f = 0; f < 4; ++f) {
            af[f]  = *(const bf16x8*)&As[(wm + f * 16 + l15) * 32 + l4 * 8];
            bfr[f] = *(const bf16x8*)&Bs[(wn + f * 16 + l15) * 32 + l4 * 8];
        }
        #pragma unroll
        for (int i = 0; i < 4; ++i)
            #pragma unroll
            for (int j = 0; j < 4; ++j)
                acc[i][j] = __builtin_amdgcn_mfma_f32_16x16x32_bf16(af[i], bfr[j], acc[i][j], 0, 0, 0);
        __syncthreads();
    }

    #pragma unroll
    for (int i = 0; i < 4; ++i) {
        int row0 = bm + wm + i * 16 + l4 * 4;
        #pragma unroll
        for (int j = 0; j < 4; ++j) {
            int col = bn + wn + j * 16 + l15;
            float bsv = bias[col];
            #pragma unroll
            for (int r = 0; r < 4; ++r) {
                size_t row = row0 + r;
                float v = acc[i][j][r] + bsv;
                if (ACT) v = v / (1.0f + expf(-v));
                if (RESID) v += resid[row * N + col];
                C[row * N + col] = v;
            }
        }
    }
}

// ---------------- rotary cos/sin tables ----------------
__global__ void k_cossin(float* __restrict__ cosb, float* __restrict__ sinb) {
    int idx = blockIdx.x * 256 + threadIdx.x;
    if (idx >= NIN * 16) return;
    int n = idx / 16, i = idx % 16;
    double inv = pow(10000.0, -(double)(2 * i) / (double)ROT);
    double f = (double)n * inv;
    cosb[idx] = (float)cos(f);
    sinb[idx] = (float)sin(f);
}

// ---------------- qs = qk*gamma+beta (4 heads) + rotary ----------------
__global__ void k_rot(const float* __restrict__ qk, const float* __restrict__ gm,
                      const float* __restrict__ bt, const float* __restrict__ cosb,
                      const float* __restrict__ sinb, float* __restrict__ q4) {
    int bn = blockIdx.x; int n = bn % NIN;
    int d = threadIdx.x;   // 128
    float x = qk[(size_t)bn * QKD + d];
    float xp0 = 0.f;
    int dp = d ^ 1;
    if (d < ROT) xp0 = qk[(size_t)bn * QKD + dp];
    #pragma unroll
    for (int c = 0; c < 4; ++c) {
        float val = x * gm[c * QKD + d] + bt[c * QKD + d];
        float outv;
        if (d < ROT) {
            int i = d >> 1;
            float cs = cosb[n * 16 + i], sn = sinb[n * 16 + i];
            float xp = xp0 * gm[c * QKD + dp] + bt[c * QKD + dp];
            outv = ((d & 1) == 0) ? (val * cs - xp * sn) : (val * cs + xp * sn);
        } else outv = val;
        q4[((size_t)bn * 4 + c) * QKD + d] = outv;
    }
}

// ---------------- fused grouped attention, bf16 output ----------------
__global__ __launch_bounds__(256) void k_attn(const float* __restrict__ q4,
        const float* __restrict__ hid, const float* __restrict__ rp,
        unsigned short* __restrict__ attn_out) {
    int et = blockIdx.x, g = blockIdx.y, b = blockIdx.z;
    int tid = threadIdx.x;
    __shared__ float Qq[32][QKD + 4], Lq[32][QKD + 4], Kt[32][QKD + 4];
    __shared__ float S[32][32];
    __shared__ float rps[GSZ];
    if (tid < GSZ) rps[tid] = rp[tid] * sqrtf((float)QKD);
    size_t base = (size_t)b * NIN + (size_t)g * GSZ;
    for (int it = tid; it < 32 * 32; it += 256) {
        int i = it / 32, f4 = it % 32;
        ((float4*)Qq[i])[f4] = ((const float4*)(q4 + ((base + i) * 4 + 0) * QKD))[f4];
        ((float4*)Lq[i])[f4] = ((const float4*)(q4 + ((base + i) * 4 + 1) * QKD))[f4];
    }
    float acc[32];
    #pragma unroll
    for (int i = 0; i < 32; ++i) acc[i] = 0.f;
    int e = et * 256 + tid;
    for (int gp = 0; gp <= g; ++gp) {
        bool quad = (gp == g);
        size_t kbase = (size_t)b * NIN + (size_t)gp * GSZ;
        int c = quad ? 2 : 3;
        __syncthreads();
        for (int it = tid; it < 32 * 32; it += 256) {
            int i = it / 32, f4 = it % 32;
            ((float4*)Kt[i])[f4] = ((const float4*)(q4 + ((kbase + i) * 4 + c) * QKD))[f4];
        }
        __syncthreads();
        for (int it = tid; it < 1024; it += 256) {
            int i = it / 32, j = it % 32;
            const float* Qrow = quad ? Qq[i] : Lq[i];
            float s = 0.f;
            #pragma unroll
            for (int d = 0; d < QKD; d += 4) {
                float4 qv = *(const float4*)&Qrow[d];
                float4 kv = *(const float4*)&Kt[j][d];
                s += qv.x * kv.x + qv.y * kv.y + qv.z * kv.z + qv.w * kv.w;
            }
            s *= (1.0f / GSZ);
            if (quad) {
                int neg = i - j;
                if (j > i) s = 0.f;
                else {
                    int bucket;
                    if (neg < 16) bucket = neg;
                    else {
                        bucket = 16 + (int)(logf((float)neg * (1.0f / 16.0f)) * (16.0f / logf(8.0f)));
                        if (bucket > 31) bucket = 31;
                    }
                    s += rps[bucket];
                    s = fmaxf(s, 0.f);
                    s = s * s;
                }
            }
            S[i][j] = s;
        }
        __syncthreads();
        const float* vcol = hid + kbase * HID2 + e;
        #pragma unroll 4
        for (int j = 0; j < 32; ++j) {
            float vv = vcol[(size_t)j * HID2];
            #pragma unroll
            for (int i = 0; i < 32; ++i) acc[i] += S[i][j] * vv;
        }
    }
    #pragma unroll
    for (int i = 0; i < 32; ++i) {
        size_t row = base + i;
        float gate = hid[row * HID2 + HID + e];
        attn_out[row * HID + e] = f2bf(gate * acc[i]);
    }
}

// ---------------- final LayerNorm ----------------
__global__ void k_ln(const float* __restrict__ h, const float* __restrict__ lng,
                     const float* __restrict__ lnb, float* __restrict__ out) {
    int bn = blockIdx.x;
    int t = threadIdx.x;   // 128
    const float4* r4 = (const float4*)(h + (size_t)bn * DIMD);
    float4 v = r4[t];
    float s  = v.x + v.y + v.z + v.w;
    float sq = v.x * v.x + v.y * v.y + v.z * v.z + v.w * v.w;
    __shared__ float red[4];
    #pragma unroll
    for (int o = 32; o; o >>= 1) { s += __shfl_down(s, o); sq += __shfl_down(sq, o); }
    int lane = t & 63, w = t >> 6;
    if (lane == 0) { red[w] = s; red[2 + w] = sq; }
    __syncthreads();
    float mu  = (red[0] + red[1]) * (1.0f / DIMD);
    float var = (red[2] + red[3]) * (1.0f / DIMD) - mu * mu;
    float rstd = 1.0f / sqrtf(var + EPSF);
    float4 gg = ((const float4*)lng)[t];
    float4 bb = ((const float4*)lnb)[t];
    float4 o;
    o.x = (v.x - mu) * rstd * gg.x + bb.x;
    o.y = (v.y - mu) * rstd * gg.y + bb.y;
    o.z = (v.z - mu) * rstd * gg.z + bb.z;
    o.w = (v.w - mu) * rstd * gg.w + bb.w;
    ((float4*)(out + (size_t)bn * DIMD))[t] = o;
}

extern "C" void kernel_launch(void* const* d_in, const int* in_sizes, int n_in,
                              void* d_out, int out_size, void* d_ws, size_t ws_size,
                              hipStream_t stream) {
    const int*   tokens = (const int*)d_in[0];
    const float* emb    = (const float*)d_in[1];
    const float* pos    = (const float*)d_in[2];
    const float* norm_g = (const float*)d_in[3];
    const float* Wh     = (const float*)d_in[4];
    const float* bh     = (const float*)d_in[5];
    const float* Wqk    = (const float*)d_in[6];
    const float* bqk    = (const float*)d_in[7];
    const float* gamma  = (const float*)d_in[8];
    const float* beta   = (const float*)d_in[9];
    const float* rp     = (const float*)d_in[10];
    const float* Wout   = (const float*)d_in[11];
    const float* bout   = (const float*)d_in[12];
    const float* lng    = (const float*)d_in[13];
    const float* lnb    = (const float*)d_in[14];

    float* h  = (float*)d_out;
    float* ws = (float*)d_ws;

    // ---- fixed allocations ----
    size_t off = 0;
    float* scale = ws + off; off += (size_t)BB * NIN;
    float* cosb  = ws + off; off += NIN * 16;
    float* sinb  = ws + off; off += NIN * 16;
    unsigned short* whT   = (unsigned short*)(ws + off); off += (size_t)NLAYER * HID2 * DIMD / 2;
    unsigned short* wqkT  = (unsigned short*)(ws + off); off += (size_t)NLAYER * QKD * DIMD / 2;
    unsigned short* woutT = (unsigned short*)(ws + off); off += (size_t)NLAYER * DIMD * HID / 2;
    off = (off + 63) & ~(size_t)63;
    const size_t fixedFloats = off;

    // ---- size batch chunk from remaining ws ----
    const size_t wsFloats = ws_size / sizeof(float);
    // per row: nx bf16(256f) + hid f32(2048f) + qk f32(128f) + q4 f32(512f) + attn bf16(512f)
    const size_t perBatch = (size_t)NIN * (DIMD / 2 + HID2 + QKD + DIMD + HID / 2);
    int CB = BB;
    while (CB > 1 && fixedFloats + (size_t)CB * perBatch + 64 > wsFloats) CB >>= 1;

    unsigned short* nx = (unsigned short*)(ws + off); off += (size_t)CB * NIN * DIMD / 2;
    float* hid  = ws + off; off += (size_t)CB * NIN * HID2;
    float* qk   = ws + off; off += (size_t)CB * NIN * QKD;
    float* q4   = ws + off; off += (size_t)CB * NIN * DIMD;   // 4 heads x 128
    unsigned short* attnB = (unsigned short*)(ws + off); off += (size_t)CB * NIN * HID / 2;

    const int BN_ = BB * NIN;

    k_cossin<<<8, 256, 0, stream>>>(cosb, sinb);
    k_embed<<<BN_, 128, 0, stream>>>(tokens, emb, pos, h);

    // convert + transpose all weights to bf16 once
    for (int l = 0; l < NLAYER; ++l) {
        k_wcast<<<(HID2 * DIMD / 8 + 255) / 256, 256, 0, stream>>>(
            Wh + (size_t)l * DIMD * HID2,  whT  + (size_t)l * HID2 * DIMD, DIMD, HID2);
        k_wcast<<<(QKD * DIMD / 8 + 255) / 256, 256, 0, stream>>>(
            Wqk + (size_t)l * DIMD * QKD,  wqkT + (size_t)l * QKD * DIMD, DIMD, QKD);
        k_wcast<<<(DIMD * HID / 8 + 255) / 256, 256, 0, stream>>>(
            Wout + (size_t)l * HID * DIMD, woutT + (size_t)l * DIMD * HID, HID, DIMD);
    }

    for (int l = 0; l < NLAYER; ++l) {
        const float* bh_l  = bh   + (size_t)l * HID2;
        const float* bqk_l = bqk  + (size_t)l * QKD;
        const float* gm_l  = gamma+ (size_t)l * 4 * QKD;
        const float* bt_l  = beta + (size_t)l * 4 * QKD;
        const float* rp_l  = rp   + (size_t)l * 32;
        const float* bo_l  = bout + (size_t)l * DIMD;
        const unsigned short* whT_l   = whT   + (size_t)l * HID2 * DIMD;
        const unsigned short* wqkT_l  = wqkT  + (size_t)l * QKD * DIMD;
        const unsigned short* woutT_l = woutT + (size_t)l * DIMD * HID;

        for (int c0 = 0; c0 < BB; c0 += CB) {
            const int rowsC = CB * NIN;
            float* h_c = h + (size_t)c0 * NIN * DIMD;

            k_rms<<<rowsC / 4, 256, 0, stream>>>(h_c, scale, norm_g + l);
            k_nx<<<rowsC, 128, 0, stream>>>(h_c, scale, nx);

            dim3 g1(HID2 / 128, rowsC / 128);
            k_gemm_bf16<1, 0><<<g1, 256, 0, stream>>>(nx, whT_l, bh_l, nullptr, hid,
                                                      rowsC, HID2, DIMD);
            dim3 g2(QKD / 128, rowsC / 128);
            k_gemm_bf16<1, 0><<<g2, 256, 0, stream>>>(nx, wqkT_l, bqk_l, nullptr, qk,
                                                      rowsC, QKD, DIMD);

            k_rot<<<rowsC, 128, 0, stream>>>(qk, gm_l, bt_l, cosb, sinb, q4);

            dim3 ga(HID / 256, GRP, CB);
            k_attn<<<ga, 256, 0, stream>>>(q4, hid, rp_l, attnB);

            dim3 g3(DIMD / 128, rowsC / 128);
            k_gemm_bf16<0, 1><<<g3, 256, 0, stream>>>(attnB, woutT_l, bo_l, h_c, h_c,
                                                      rowsC, DIMD, HID);
        }
    }

    k_ln<<<BN_, 128, 0, stream>>>(h, lng, lnb, (float*)d_out);
}

// Round 6
// 1722.174 us; speedup vs baseline: 4.4691x; 1.7563x over previous
//
#include <hip/hip_runtime.h>
#include <hip/hip_bf16.h>
#include <math.h>
#include <stdint.h>

#define BB   512
#define NIN  128
#define DIMD 512
#define QKD  128
#define GSZ  32
#define GRP  4
#define HID  1024
#define HID2 2048
#define ROT  32
#define NLAYER 2
#define EPSF 1e-5f
#define BINS 100

typedef __bf16 bf16x8 __attribute__((ext_vector_type(8)));
typedef float  f32x4  __attribute__((ext_vector_type(4)));
typedef float  f32x16 __attribute__((ext_vector_type(16)));

__device__ __forceinline__ unsigned short f2bf(float f) {
    union { float f; uint32_t u; } v; v.f = f;
    return (unsigned short)((v.u + 0x7FFFu + ((v.u >> 16) & 1u)) >> 16);
}
__device__ __forceinline__ float bf2f(unsigned short h) {
    union { uint32_t u; float f; } v; v.u = ((uint32_t)h) << 16;
    return v.f;
}

// ---------------- embedding ----------------
__global__ void k_embed(const int* __restrict__ tokens, const float* __restrict__ emb,
                        const float* __restrict__ pos, float* __restrict__ h) {
    int bn = blockIdx.x;
    int n  = bn % NIN;
    int tok = tokens[bn];
    const float4* e4 = (const float4*)(emb + ((size_t)n * BINS + tok) * DIMD);
    const float4* p4 = (const float4*)(pos + (size_t)n * DIMD);
    float4* h4 = (float4*)(h + (size_t)bn * DIMD);
    int t = threadIdx.x;
    float4 a = e4[t], b = p4[t];
    h4[t] = make_float4(a.x + b.x, a.y + b.y, a.z + b.z, a.w + b.w);
}

// ---------------- RMS scale ----------------
__global__ void k_rms(const float* __restrict__ h, float* __restrict__ scale,
                      const float* __restrict__ ngp) {
    int row  = blockIdx.x * 4 + (threadIdx.x >> 6);
    int lane = threadIdx.x & 63;
    const float4* r4 = (const float4*)(h + (size_t)row * DIMD);
    float s = 0.f;
    #pragma unroll
    for (int i = 0; i < 2; ++i) {
        float4 v = r4[lane + 64 * i];
        s += v.x * v.x + v.y * v.y + v.z * v.z + v.w * v.w;
    }
    #pragma unroll
    for (int o = 32; o; o >>= 1) s += __shfl_down(s, o);
    if (lane == 0) {
        float nrm = sqrtf(s) * (1.0f / sqrtf((float)DIMD));
        scale[row] = ngp[0] / fmaxf(nrm, EPSF);
    }
}

// ---------------- build nx in bf16 (half-shifted) ----------------
__global__ void k_nx(const float* __restrict__ h, const float* __restrict__ scale,
                     unsigned short* __restrict__ nx) {
    int bn = blockIdx.x; int n = bn % NIN;
    int t = threadIdx.x;   // 128 threads x 4 elems
    float4 v; float sc;
    if (t < 64) {
        if (n == 0) {
            ((ushort4*)(nx + (size_t)bn * DIMD))[t] = make_ushort4(0, 0, 0, 0);
            return;
        }
        sc = scale[bn - 1];
        v = ((const float4*)(h + (size_t)(bn - 1) * DIMD))[t];
    } else {
        sc = scale[bn];
        v = ((const float4*)(h + (size_t)bn * DIMD))[t];
    }
    ushort4 o = make_ushort4(f2bf(v.x * sc), f2bf(v.y * sc), f2bf(v.z * sc), f2bf(v.w * sc));
    ((ushort4*)(nx + (size_t)bn * DIMD))[t] = o;
}

// ---------------- weight cast+transpose: Wt[n][k] = bf16(W[k][n]) ----------------
__global__ void k_wcast(const float* __restrict__ W, unsigned short* __restrict__ Wt,
                        int K, int N) {
    int idx = blockIdx.x * 256 + threadIdx.x;
    int total = N * (K / 8);
    if (idx >= total) return;
    int kb = idx / N, n = idx % N;
    #pragma unroll
    for (int j = 0; j < 8; ++j)
        Wt[(size_t)n * K + kb * 8 + j] = f2bf(W[(size_t)(kb * 8 + j) * N + n]);
}

// ---------------- bf16 MFMA GEMM: C = act(A@Bt^T + bias) [+resid] ----------------
#define GLOAD_LDS(gp, lp) __builtin_amdgcn_global_load_lds( \
    (const __attribute__((address_space(1))) uint32_t*)(gp), \
    (__attribute__((address_space(3))) uint32_t*)(lp), 16, 0, 0)

template<int ACT, int RESID, int OUTBF>
__global__ __launch_bounds__(256) void k_gemm_bf16(
        const unsigned short* __restrict__ A,
        const unsigned short* __restrict__ Bt,
        const float* __restrict__ bias,
        const float* __restrict__ resid,
        void* __restrict__ Cp,
        int M, int N, int K) {
    __shared__ unsigned short As[128 * 32];
    __shared__ unsigned short Bs[128 * 32];
    const int tid  = threadIdx.x;
    const int bm   = blockIdx.y * 128, bn = blockIdx.x * 128;
    const int lane = tid & 63, wave = tid >> 6;
    const int wm = (wave >> 1) * 64, wn = (wave & 1) * 64;
    const int l15 = lane & 15, l4 = lane >> 4;

    f32x4 acc[4][4];
    #pragma unroll
    for (int i = 0; i < 4; ++i)
        #pragma unroll
        for (int j = 0; j < 4; ++j) acc[i][j] = (f32x4){0.f, 0.f, 0.f, 0.f};

    const int rowA = tid >> 2;
    const int colB = (tid & 3) * 16;
    const char* gA = (const char*)(A  + (size_t)(bm + rowA) * K) + colB;
    const char* gB = (const char*)(Bt + (size_t)(bn + rowA) * K) + colB;
    const size_t stride64 = (size_t)64 * K * 2;
    unsigned short* ldsA = As + tid * 8;
    unsigned short* ldsB = Bs + tid * 8;

    for (int k0 = 0; k0 < K; k0 += 32) {
        GLOAD_LDS(gA + (size_t)k0 * 2,            ldsA);
        GLOAD_LDS(gA + (size_t)k0 * 2 + stride64, ldsA + 2048);
        GLOAD_LDS(gB + (size_t)k0 * 2,            ldsB);
        GLOAD_LDS(gB + (size_t)k0 * 2 + stride64, ldsB + 2048);
        asm volatile("s_waitcnt vmcnt(0)" ::: "memory");
        __syncthreads();

        bf16x8 af[4], bfr[4];
        #pragma unroll
        for (int f = 0; f < 4; ++f) {
            af[f]  = *(const bf16x8*)&As[(wm + f * 16 + l15) * 32 + l4 * 8];
            bfr[f] = *(const bf16x8*)&Bs[(wn + f * 16 + l15) * 32 + l4 * 8];
        }
        #pragma unroll
        for (int i = 0; i < 4; ++i)
            #pragma unroll
            for (int j = 0; j < 4; ++j)
                acc[i][j] = __builtin_amdgcn_mfma_f32_16x16x32_bf16(af[i], bfr[j], acc[i][j], 0, 0, 0);
        __syncthreads();
    }

    #pragma unroll
    for (int i = 0; i < 4; ++i) {
        int row0 = bm + wm + i * 16 + l4 * 4;
        #pragma unroll
        for (int j = 0; j < 4; ++j) {
            int col = bn + wn + j * 16 + l15;
            float bsv = bias[col];
            #pragma unroll
            for (int r = 0; r < 4; ++r) {
                size_t row = row0 + r;
                float v = acc[i][j][r] + bsv;
                if (ACT) v = v / (1.0f + expf(-v));
                if (RESID) v += resid[row * N + col];
                if (OUTBF) ((unsigned short*)Cp)[row * N + col] = f2bf(v);
                else       ((float*)Cp)[row * N + col] = v;
            }
        }
    }
}

// ---------------- rotary cos/sin tables ----------------
__global__ void k_cossin(float* __restrict__ cosb, float* __restrict__ sinb) {
    int idx = blockIdx.x * 256 + threadIdx.x;
    if (idx >= NIN * 16) return;
    int n = idx / 16, i = idx % 16;
    double inv = pow(10000.0, -(double)(2 * i) / (double)ROT);
    double f = (double)n * inv;
    cosb[idx] = (float)cos(f);
    sinb[idx] = (float)sin(f);
}

// ---------------- qs = qk*gamma+beta (4 heads) + rotary, bf16 out ----------------
__global__ void k_rot(const float* __restrict__ qk, const float* __restrict__ gm,
                      const float* __restrict__ bt, const float* __restrict__ cosb,
                      const float* __restrict__ sinb, unsigned short* __restrict__ q4) {
    int bn = blockIdx.x; int n = bn % NIN;
    int d = threadIdx.x;   // 128
    float x = qk[(size_t)bn * QKD + d];
    float xp0 = 0.f;
    int dp = d ^ 1;
    if (d < ROT) xp0 = qk[(size_t)bn * QKD + dp];
    #pragma unroll
    for (int c = 0; c < 4; ++c) {
        float val = x * gm[c * QKD + d] + bt[c * QKD + d];
        float outv;
        if (d < ROT) {
            int i = d >> 1;
            float cs = cosb[n * 16 + i], sn = sinb[n * 16 + i];
            float xp = xp0 * gm[c * QKD + dp] + bt[c * QKD + dp];
            outv = ((d & 1) == 0) ? (val * cs - xp * sn) : (val * cs + xp * sn);
        } else outv = val;
        q4[((size_t)bn * 4 + c) * QKD + d] = f2bf(outv);
    }
}

// ---------------- V transpose: vT[b][e][n] = hid_bf16[b*128+n][e] (e<1024) ----------------
__global__ __launch_bounds__(256) void k_vt(const unsigned short* __restrict__ hid,
                                            unsigned short* __restrict__ vT) {
    int eblk = blockIdx.x;       // 8 tiles of 128 e
    int b    = blockIdx.y;
    int t    = threadIdx.x;
    __shared__ unsigned short tile[128][136];
    int e0 = eblk * 128;
    int nsub = t >> 5;           // 0..7
    int e4   = (t & 31) * 4;
    #pragma unroll
    for (int r = 0; r < 128; r += 8) {
        int n = r + nsub;
        ushort4 v = *(const ushort4*)&hid[((size_t)b * NIN + n) * HID2 + e0 + e4];
        *(ushort4*)&tile[n][e4] = v;
    }
    __syncthreads();
    #pragma unroll
    for (int r = 0; r < 128; r += 8) {
        int e = r + nsub;
        ushort4 o;
        o.x = tile[e4 + 0][e]; o.y = tile[e4 + 1][e];
        o.z = tile[e4 + 2][e]; o.w = tile[e4 + 3][e];
        *(ushort4*)&vT[((size_t)b * HID + e0 + e) * NIN + e4] = o;
    }
}

// ---------------- MFMA fused attention ----------------
// grid (HID/256, CB); 256 threads = 4 waves; wave w owns e-cols [w*64, w*64+64).
__global__ __launch_bounds__(256) void k_attn2(
        const unsigned short* __restrict__ q4,   // [(b*128+n)*4 + c][128] bf16
        const unsigned short* __restrict__ hid,  // [b*128+n][2048] bf16 (gate at 1024+)
        const unsigned short* __restrict__ vT,   // [b][e][n] bf16
        const float* __restrict__ rp,
        unsigned short* __restrict__ attn_out) { // [b*128+n][1024] bf16
    int et = blockIdx.x, b = blockIdx.y;
    int tid = threadIdx.x, wave = tid >> 6, lane = tid & 63;
    int l31 = lane & 31, lhi = lane >> 5;

    __shared__ unsigned short S[32][136];
    __shared__ float rps_d[32];
    if (tid < 32) {
        int d = tid, bucket;
        if (d < 16) bucket = d;
        else {
            bucket = 16 + (int)(logf((float)d * (1.0f / 16.0f)) * (16.0f / logf(8.0f)));
            if (bucket > 31) bucket = 31;
        }
        rps_d[tid] = rp[bucket] * sqrtf((float)QKD);
    }
    __syncthreads();

    size_t bbase = (size_t)b * NIN;
    int e0 = et * 256 + wave * 64;
    const unsigned short* vbase = vT + (size_t)b * HID * NIN;

    for (int g = 0; g < GRP; ++g) {
        // ---- phase A: S tiles (wave w computes pair gp=w, quad when w==g) ----
        if (wave <= g) {
            int gp = wave;
            bool quad = (gp == g);
            const unsigned short* Qb = q4 + ((bbase + g  * 32 + l31) * 4 + (quad ? 0 : 1)) * QKD;
            const unsigned short* Kb = q4 + ((bbase + gp * 32 + l31) * 4 + (quad ? 2 : 3)) * QKD;
            f32x16 sa = {};
            #pragma unroll
            for (int kk = 0; kk < 8; ++kk) {
                bf16x8 aq = *(const bf16x8*)(Qb + kk * 16 + lhi * 8);
                bf16x8 bk = *(const bf16x8*)(Kb + kk * 16 + lhi * 8);
                sa = __builtin_amdgcn_mfma_f32_32x32x16_bf16(aq, bk, sa, 0, 0, 0);
            }
            int j = l31;
            #pragma unroll
            for (int r = 0; r < 16; ++r) {
                int i = (r & 3) + 8 * (r >> 2) + 4 * lhi;
                float s = sa[r] * (1.0f / GSZ);
                if (quad) {
                    if (j > i) s = 0.f;
                    else {
                        s += rps_d[i - j];
                        s = fmaxf(s, 0.f);
                        s = s * s;
                    }
                }
                S[i][gp * 32 + j] = f2bf(s);
            }
        }
        __syncthreads();

        // ---- phase B: PV over K = 32*(g+1) ----
        f32x16 o0 = {}, o1 = {};
        int KT = 2 * (g + 1);
        for (int kk = 0; kk < KT; ++kk) {
            int k0 = kk * 16 + lhi * 8;
            bf16x8 af = *(const bf16x8*)&S[l31][k0];
            bf16x8 b0 = *(const bf16x8*)(vbase + (size_t)(e0 + l31) * NIN + k0);
            bf16x8 b1 = *(const bf16x8*)(vbase + (size_t)(e0 + 32 + l31) * NIN + k0);
            o0 = __builtin_amdgcn_mfma_f32_32x32x16_bf16(af, b0, o0, 0, 0, 0);
            o1 = __builtin_amdgcn_mfma_f32_32x32x16_bf16(af, b1, o1, 0, 0, 0);
        }
        __syncthreads();   // S reused next g

        // ---- epilogue: gate + store (rows g*32 + i) ----
        int ea = e0 + l31, eb = e0 + 32 + l31;
        #pragma unroll
        for (int r = 0; r < 16; ++r) {
            int i = (r & 3) + 8 * (r >> 2) + 4 * lhi;
            size_t row = bbase + g * 32 + i;
            float ga = bf2f(hid[row * HID2 + HID + ea]);
            float gb = bf2f(hid[row * HID2 + HID + eb]);
            attn_out[row * HID + ea] = f2bf(ga * o0[r]);
            attn_out[row * HID + eb] = f2bf(gb * o1[r]);
        }
    }
}

// ---------------- final LayerNorm ----------------
__global__ void k_ln(const float* __restrict__ h, const float* __restrict__ lng,
                     const float* __restrict__ lnb, float* __restrict__ out) {
    int bn = blockIdx.x;
    int t = threadIdx.x;   // 128
    const float4* r4 = (const float4*)(h + (size_t)bn * DIMD);
    float4 v = r4[t];
    float s  = v.x + v.y + v.z + v.w;
    float sq = v.x * v.x + v.y * v.y + v.z * v.z + v.w * v.w;
    __shared__ float red[4];
    #pragma unroll
    for (int o = 32; o; o >>= 1) { s += __shfl_down(s, o); sq += __shfl_down(sq, o); }
    int lane = t & 63, w = t >> 6;
    if (lane == 0) { red[w] = s; red[2 + w] = sq; }
    __syncthreads();
    float mu  = (red[0] + red[1]) * (1.0f / DIMD);
    float var = (red[2] + red[3]) * (1.0f / DIMD) - mu * mu;
    float rstd = 1.0f / sqrtf(var + EPSF);
    float4 gg = ((const float4*)lng)[t];
    float4 bb = ((const float4*)lnb)[t];
    float4 o;
    o.x = (v.x - mu) * rstd * gg.x + bb.x;
    o.y = (v.y - mu) * rstd * gg.y + bb.y;
    o.z = (v.z - mu) * rstd * gg.z + bb.z;
    o.w = (v.w - mu) * rstd * gg.w + bb.w;
    ((float4*)(out + (size_t)bn * DIMD))[t] = o;
}

extern "C" void kernel_launch(void* const* d_in, const int* in_sizes, int n_in,
                              void* d_out, int out_size, void* d_ws, size_t ws_size,
                              hipStream_t stream) {
    const int*   tokens = (const int*)d_in[0];
    const float* emb    = (const float*)d_in[1];
    const float* pos    = (const float*)d_in[2];
    const float* norm_g = (const float*)d_in[3];
    const float* Wh     = (const float*)d_in[4];
    const float* bh     = (const float*)d_in[5];
    const float* Wqk    = (const float*)d_in[6];
    const float* bqk    = (const float*)d_in[7];
    const float* gamma  = (const float*)d_in[8];
    const float* beta   = (const float*)d_in[9];
    const float* rp     = (const float*)d_in[10];
    const float* Wout   = (const float*)d_in[11];
    const float* bout   = (const float*)d_in[12];
    const float* lng    = (const float*)d_in[13];
    const float* lnb    = (const float*)d_in[14];

    float* h  = (float*)d_out;
    float* ws = (float*)d_ws;

    // ---- fixed allocations ----
    size_t off = 0;
    float* scale = ws + off; off += (size_t)BB * NIN;
    float* cosb  = ws + off; off += NIN * 16;
    float* sinb  = ws + off; off += NIN * 16;
    unsigned short* whT   = (unsigned short*)(ws + off); off += (size_t)NLAYER * HID2 * DIMD / 2;
    unsigned short* wqkT  = (unsigned short*)(ws + off); off += (size_t)NLAYER * QKD * DIMD / 2;
    unsigned short* woutT = (unsigned short*)(ws + off); off += (size_t)NLAYER * DIMD * HID / 2;
    off = (off + 63) & ~(size_t)63;
    const size_t fixedFloats = off;

    // ---- size batch chunk ----
    const size_t wsFloats = ws_size / sizeof(float);
    // per batch (floats): nx bf16(256) + hid bf16(1024) + qk f32(128) + q4 bf16(256) + vT bf16(512) + attn bf16(512)
    const size_t perBatch = (size_t)NIN * (DIMD / 2 + HID2 / 2 + QKD + DIMD / 2 + HID / 2 + HID / 2);
    int CB = BB;
    while (CB > 1 && fixedFloats + (size_t)CB * perBatch + 64 > wsFloats) CB >>= 1;

    unsigned short* nx    = (unsigned short*)(ws + off); off += (size_t)CB * NIN * DIMD / 2;
    unsigned short* hid   = (unsigned short*)(ws + off); off += (size_t)CB * NIN * HID2 / 2;
    float*          qk    = ws + off;                    off += (size_t)CB * NIN * QKD;
    unsigned short* q4    = (unsigned short*)(ws + off); off += (size_t)CB * NIN * DIMD / 2;
    unsigned short* vT    = (unsigned short*)(ws + off); off += (size_t)CB * HID * NIN / 2;
    unsigned short* attnB = (unsigned short*)(ws + off); off += (size_t)CB * NIN * HID / 2;

    const int BN_ = BB * NIN;

    k_cossin<<<8, 256, 0, stream>>>(cosb, sinb);
    k_embed<<<BN_, 128, 0, stream>>>(tokens, emb, pos, h);

    for (int l = 0; l < NLAYER; ++l) {
        k_wcast<<<(HID2 * DIMD / 8 + 255) / 256, 256, 0, stream>>>(
            Wh + (size_t)l * DIMD * HID2,  whT  + (size_t)l * HID2 * DIMD, DIMD, HID2);
        k_wcast<<<(QKD * DIMD / 8 + 255) / 256, 256, 0, stream>>>(
            Wqk + (size_t)l * DIMD * QKD,  wqkT + (size_t)l * QKD * DIMD, DIMD, QKD);
        k_wcast<<<(DIMD * HID / 8 + 255) / 256, 256, 0, stream>>>(
            Wout + (size_t)l * HID * DIMD, woutT + (size_t)l * DIMD * HID, HID, DIMD);
    }

    for (int l = 0; l < NLAYER; ++l) {
        const float* bh_l  = bh   + (size_t)l * HID2;
        const float* bqk_l = bqk  + (size_t)l * QKD;
        const float* gm_l  = gamma+ (size_t)l * 4 * QKD;
        const float* bt_l  = beta + (size_t)l * 4 * QKD;
        const float* rp_l  = rp   + (size_t)l * 32;
        const float* bo_l  = bout + (size_t)l * DIMD;
        const unsigned short* whT_l   = whT   + (size_t)l * HID2 * DIMD;
        const unsigned short* wqkT_l  = wqkT  + (size_t)l * QKD * DIMD;
        const unsigned short* woutT_l = woutT + (size_t)l * DIMD * HID;

        for (int c0 = 0; c0 < BB; c0 += CB) {
            const int rowsC = CB * NIN;
            float* h_c = h + (size_t)c0 * NIN * DIMD;

            k_rms<<<rowsC / 4, 256, 0, stream>>>(h_c, scale, norm_g + l);
            k_nx<<<rowsC, 128, 0, stream>>>(h_c, scale, nx);

            dim3 g1(HID2 / 128, rowsC / 128);
            k_gemm_bf16<1, 0, 1><<<g1, 256, 0, stream>>>(nx, whT_l, bh_l, nullptr, hid,
                                                         rowsC, HID2, DIMD);
            dim3 g2(QKD / 128, rowsC / 128);
            k_gemm_bf16<1, 0, 0><<<g2, 256, 0, stream>>>(nx, wqkT_l, bqk_l, nullptr, qk,
                                                         rowsC, QKD, DIMD);

            k_rot<<<rowsC, 128, 0, stream>>>(qk, gm_l, bt_l, cosb, sinb, q4);

            dim3 gv(HID / 128, CB);
            k_vt<<<gv, 256, 0, stream>>>(hid, vT);

            dim3 ga(HID / 256, CB);
            k_attn2<<<ga, 256, 0, stream>>>(q4, hid, vT, rp_l, attnB);

            dim3 g3(DIMD / 128, rowsC / 128);
            k_gemm_bf16<0, 1, 0><<<g3, 256, 0, stream>>>(attnB, woutT_l, bo_l, h_c, h_c,
                                                         rowsC, DIMD, HID);
        }
    }

    k_ln<<<BN_, 128, 0, stream>>>(h, lng, lnb, (float*)d_out);
}

// Round 7
// 1522.626 us; speedup vs baseline: 5.0547x; 1.1311x over previous
//
#include <hip/hip_runtime.h>
#include <hip/hip_bf16.h>
#include <math.h>
#include <stdint.h>

#define BB   512
#define NIN  128
#define DIMD 512
#define QKD  128
#define GSZ  32
#define GRP  4
#define HID  1024
#define HID2 2048
#define NFUSE 2176   // HID2 + QKD
#define ROT  32
#define NLAYER 2
#define EPSF 1e-5f
#define BINS 100

typedef __bf16 bf16x8 __attribute__((ext_vector_type(8)));
typedef float  f32x4  __attribute__((ext_vector_type(4)));
typedef float  f32x16 __attribute__((ext_vector_type(16)));

__device__ __forceinline__ unsigned short f2bf(float f) {
    union { float f; uint32_t u; } v; v.f = f;
    return (unsigned short)((v.u + 0x7FFFu + ((v.u >> 16) & 1u)) >> 16);
}
__device__ __forceinline__ float bf2f(unsigned short h) {
    union { uint32_t u; float f; } v; v.u = ((uint32_t)h) << 16;
    return v.f;
}

// ---------------- embedding ----------------
__global__ void k_embed(const int* __restrict__ tokens, const float* __restrict__ emb,
                        const float* __restrict__ pos, float* __restrict__ h) {
    int bn = blockIdx.x;
    int n  = bn % NIN;
    int tok = tokens[bn];
    const float4* e4 = (const float4*)(emb + ((size_t)n * BINS + tok) * DIMD);
    const float4* p4 = (const float4*)(pos + (size_t)n * DIMD);
    float4* h4 = (float4*)(h + (size_t)bn * DIMD);
    int t = threadIdx.x;
    float4 a = e4[t], b = p4[t];
    h4[t] = make_float4(a.x + b.x, a.y + b.y, a.z + b.z, a.w + b.w);
}

// ---------------- RMS scale ----------------
__global__ void k_rms(const float* __restrict__ h, float* __restrict__ scale,
                      const float* __restrict__ ngp) {
    int row  = blockIdx.x * 4 + (threadIdx.x >> 6);
    int lane = threadIdx.x & 63;
    const float4* r4 = (const float4*)(h + (size_t)row * DIMD);
    float s = 0.f;
    #pragma unroll
    for (int i = 0; i < 2; ++i) {
        float4 v = r4[lane + 64 * i];
        s += v.x * v.x + v.y * v.y + v.z * v.z + v.w * v.w;
    }
    #pragma unroll
    for (int o = 32; o; o >>= 1) s += __shfl_down(s, o);
    if (lane == 0) {
        float nrm = sqrtf(s) * (1.0f / sqrtf((float)DIMD));
        scale[row] = ngp[0] / fmaxf(nrm, EPSF);
    }
}

// ---------------- build nx in bf16 (half-shifted) ----------------
__global__ void k_nx(const float* __restrict__ h, const float* __restrict__ scale,
                     unsigned short* __restrict__ nx) {
    int bn = blockIdx.x; int n = bn % NIN;
    int t = threadIdx.x;
    float4 v; float sc;
    if (t < 64) {
        if (n == 0) {
            ((ushort4*)(nx + (size_t)bn * DIMD))[t] = make_ushort4(0, 0, 0, 0);
            return;
        }
        sc = scale[bn - 1];
        v = ((const float4*)(h + (size_t)(bn - 1) * DIMD))[t];
    } else {
        sc = scale[bn];
        v = ((const float4*)(h + (size_t)bn * DIMD))[t];
    }
    ushort4 o = make_ushort4(f2bf(v.x * sc), f2bf(v.y * sc), f2bf(v.z * sc), f2bf(v.w * sc));
    ((ushort4*)(nx + (size_t)bn * DIMD))[t] = o;
}

// ---------------- weight cast+transpose: Wt[n][k] = bf16(W[k][n]) ----------------
__global__ void k_wcast(const float* __restrict__ W, unsigned short* __restrict__ Wt,
                        int K, int N) {
    int idx = blockIdx.x * 256 + threadIdx.x;
    int total = N * (K / 8);
    if (idx >= total) return;
    int kb = idx / N, n = idx % N;
    #pragma unroll
    for (int j = 0; j < 8; ++j)
        Wt[(size_t)n * K + kb * 8 + j] = f2bf(W[(size_t)(kb * 8 + j) * N + n]);
}

// ---------------- bf16 MFMA GEMM ----------------
// MODE 0: fused Wh+Wqk — N=2176, silu; cols<1024 -> vT[b][e][n] bf16;
//         1024..2047 -> gate[row][e] bf16; >=2048 -> qk f32.
// MODE 1: Wout — N=512, no act, +resid, f32 C.
#define GLOAD_LDS(gp, lp) __builtin_amdgcn_global_load_lds( \
    (const __attribute__((address_space(1))) uint32_t*)(gp), \
    (__attribute__((address_space(3))) uint32_t*)(lp), 16, 0, 0)

template<int MODE>
__global__ __launch_bounds__(256) void k_gemm_bf16(
        const unsigned short* __restrict__ A,
        const unsigned short* __restrict__ Bt,
        const float* __restrict__ bias0,
        const float* __restrict__ bias1,
        const float* __restrict__ resid,
        float* __restrict__ Cf,
        unsigned short* __restrict__ vTp,
        unsigned short* __restrict__ gatep,
        int M, int N, int K) {
    __shared__ unsigned short As[128 * 32];
    __shared__ unsigned short Bs[128 * 32];
    const int tid  = threadIdx.x;

    // XCD-chunked bijective block swizzle (m204)
    int flat = blockIdx.y * gridDim.x + blockIdx.x;
    int nwg  = gridDim.x * gridDim.y;
    int q = nwg >> 3, r = nwg & 7;
    int xcd = flat & 7, idx = flat >> 3;
    int swz = (xcd < r ? xcd * (q + 1) : r * (q + 1) + (xcd - r) * q) + idx;
    const int bxi = swz % gridDim.x, byi = swz / gridDim.x;
    const int bm = byi * 128, bn = bxi * 128;

    const int lane = tid & 63, wave = tid >> 6;
    const int wm = (wave >> 1) * 64, wn = (wave & 1) * 64;
    const int l15 = lane & 15, l4 = lane >> 4;

    f32x4 acc[4][4];
    #pragma unroll
    for (int i = 0; i < 4; ++i)
        #pragma unroll
        for (int j = 0; j < 4; ++j) acc[i][j] = (f32x4){0.f, 0.f, 0.f, 0.f};

    const int rowA = tid >> 2;
    const int colB = (tid & 3) * 16;
    const char* gA = (const char*)(A  + (size_t)(bm + rowA) * K) + colB;
    const char* gB = (const char*)(Bt + (size_t)(bn + rowA) * K) + colB;
    const size_t stride64 = (size_t)64 * K * 2;
    unsigned short* ldsA = As + tid * 8;
    unsigned short* ldsB = Bs + tid * 8;

    for (int k0 = 0; k0 < K; k0 += 32) {
        GLOAD_LDS(gA + (size_t)k0 * 2,            ldsA);
        GLOAD_LDS(gA + (size_t)k0 * 2 + stride64, ldsA + 2048);
        GLOAD_LDS(gB + (size_t)k0 * 2,            ldsB);
        GLOAD_LDS(gB + (size_t)k0 * 2 + stride64, ldsB + 2048);
        asm volatile("s_waitcnt vmcnt(0)" ::: "memory");
        __syncthreads();

        bf16x8 af[4], bfr[4];
        #pragma unroll
        for (int f = 0; f < 4; ++f) {
            af[f]  = *(const bf16x8*)&As[(wm + f * 16 + l15) * 32 + l4 * 8];
            bfr[f] = *(const bf16x8*)&Bs[(wn + f * 16 + l15) * 32 + l4 * 8];
        }
        #pragma unroll
        for (int i = 0; i < 4; ++i)
            #pragma unroll
            for (int j = 0; j < 4; ++j)
                acc[i][j] = __builtin_amdgcn_mfma_f32_16x16x32_bf16(af[i], bfr[j], acc[i][j], 0, 0, 0);
        __syncthreads();
    }

    #pragma unroll
    for (int i = 0; i < 4; ++i) {
        const int n0 = wm + i * 16 + l4 * 4;       // local row base (0..127)
        #pragma unroll
        for (int j = 0; j < 4; ++j) {
            const int col = bn + wn + j * 16 + l15;
            if (MODE == 0) {
                float bsv = (col < 2 * HID) ? bias0[col] : bias1[col - 2 * HID];
                float vv[4];
                #pragma unroll
                for (int rr = 0; rr < 4; ++rr) {
                    float v = acc[i][j][rr] + bsv;
                    vv[rr] = v / (1.0f + __expf(-v));
                }
                if (col < HID) {
                    ushort4 o = make_ushort4(f2bf(vv[0]), f2bf(vv[1]), f2bf(vv[2]), f2bf(vv[3]));
                    *(ushort4*)&vTp[((size_t)byi * HID + col) * NIN + n0] = o;
                } else if (col < 2 * HID) {
                    #pragma unroll
                    for (int rr = 0; rr < 4; ++rr)
                        gatep[(size_t)(bm + n0 + rr) * HID + (col - HID)] = f2bf(vv[rr]);
                } else {
                    #pragma unroll
                    for (int rr = 0; rr < 4; ++rr)
                        Cf[(size_t)(bm + n0 + rr) * QKD + (col - 2 * HID)] = vv[rr];
                }
            } else {
                float bsv = bias0[col];
                #pragma unroll
                for (int rr = 0; rr < 4; ++rr) {
                    size_t row = bm + n0 + rr;
                    Cf[row * N + col] = acc[i][j][rr] + bsv + resid[row * N + col];
                }
            }
        }
    }
}

// ---------------- rotary cos/sin tables ----------------
__global__ void k_cossin(float* __restrict__ cosb, float* __restrict__ sinb) {
    int idx = blockIdx.x * 256 + threadIdx.x;
    if (idx >= NIN * 16) return;
    int n = idx / 16, i = idx % 16;
    double inv = pow(10000.0, -(double)(2 * i) / (double)ROT);
    double f = (double)n * inv;
    cosb[idx] = (float)cos(f);
    sinb[idx] = (float)sin(f);
}

// ---------------- qs = qk*gamma+beta (4 heads) + rotary, bf16 out ----------------
__global__ void k_rot(const float* __restrict__ qk, const float* __restrict__ gm,
                      const float* __restrict__ bt, const float* __restrict__ cosb,
                      const float* __restrict__ sinb, unsigned short* __restrict__ q4) {
    int bn = blockIdx.x; int n = bn % NIN;
    int d = threadIdx.x;   // 128
    float x = qk[(size_t)bn * QKD + d];
    float xp0 = 0.f;
    int dp = d ^ 1;
    if (d < ROT) xp0 = qk[(size_t)bn * QKD + dp];
    #pragma unroll
    for (int c = 0; c < 4; ++c) {
        float val = x * gm[c * QKD + d] + bt[c * QKD + d];
        float outv;
        if (d < ROT) {
            int i = d >> 1;
            float cs = cosb[n * 16 + i], sn = sinb[n * 16 + i];
            float xp = xp0 * gm[c * QKD + dp] + bt[c * QKD + dp];
            outv = ((d & 1) == 0) ? (val * cs - xp * sn) : (val * cs + xp * sn);
        } else outv = val;
        q4[((size_t)bn * 4 + c) * QKD + d] = f2bf(outv);
    }
}

// ---------------- MFMA fused attention ----------------
// grid (HID/256, CB); 256 threads = 4 waves; wave w owns e-cols [w*64, w*64+64).
__global__ __launch_bounds__(256) void k_attn2(
        const unsigned short* __restrict__ q4,    // [(b*128+n)*4 + c][128] bf16
        const unsigned short* __restrict__ gatep, // [b*128+n][1024] bf16
        const unsigned short* __restrict__ vT,    // [b][e][n] bf16
        const float* __restrict__ rp,
        unsigned short* __restrict__ attn_out) {  // [b*128+n][1024] bf16
    int et = blockIdx.x, b = blockIdx.y;
    int tid = threadIdx.x, wave = tid >> 6, lane = tid & 63;
    int l31 = lane & 31, lhi = lane >> 5;

    __shared__ unsigned short S[32][136];
    __shared__ float rps_d[32];
    if (tid < 32) {
        int d = tid, bucket;
        if (d < 16) bucket = d;
        else {
            bucket = 16 + (int)(logf((float)d * (1.0f / 16.0f)) * (16.0f / logf(8.0f)));
            if (bucket > 31) bucket = 31;
        }
        rps_d[tid] = rp[bucket] * sqrtf((float)QKD);
    }
    __syncthreads();

    size_t bbase = (size_t)b * NIN;
    int e0 = et * 256 + wave * 64;
    const unsigned short* vbase = vT + (size_t)b * HID * NIN;

    for (int g = 0; g < GRP; ++g) {
        if (wave <= g) {
            int gp = wave;
            bool quad = (gp == g);
            const unsigned short* Qb = q4 + ((bbase + g  * 32 + l31) * 4 + (quad ? 0 : 1)) * QKD;
            const unsigned short* Kb = q4 + ((bbase + gp * 32 + l31) * 4 + (quad ? 2 : 3)) * QKD;
            f32x16 sa = {};
            #pragma unroll
            for (int kk = 0; kk < 8; ++kk) {
                bf16x8 aq = *(const bf16x8*)(Qb + kk * 16 + lhi * 8);
                bf16x8 bk = *(const bf16x8*)(Kb + kk * 16 + lhi * 8);
                sa = __builtin_amdgcn_mfma_f32_32x32x16_bf16(aq, bk, sa, 0, 0, 0);
            }
            int j = l31;
            #pragma unroll
            for (int r = 0; r < 16; ++r) {
                int i = (r & 3) + 8 * (r >> 2) + 4 * lhi;
                float s = sa[r] * (1.0f / GSZ);
                if (quad) {
                    if (j > i) s = 0.f;
                    else {
                        s += rps_d[i - j];
                        s = fmaxf(s, 0.f);
                        s = s * s;
                    }
                }
                S[i][gp * 32 + j] = f2bf(s);
            }
        }
        __syncthreads();

        f32x16 o0 = {}, o1 = {};
        int KT = 2 * (g + 1);
        for (int kk = 0; kk < KT; ++kk) {
            int k0 = kk * 16 + lhi * 8;
            bf16x8 af = *(const bf16x8*)&S[l31][k0];
            bf16x8 b0 = *(const bf16x8*)(vbase + (size_t)(e0 + l31) * NIN + k0);
            bf16x8 b1 = *(const bf16x8*)(vbase + (size_t)(e0 + 32 + l31) * NIN + k0);
            o0 = __builtin_amdgcn_mfma_f32_32x32x16_bf16(af, b0, o0, 0, 0, 0);
            o1 = __builtin_amdgcn_mfma_f32_32x32x16_bf16(af, b1, o1, 0, 0, 0);
        }
        __syncthreads();

        int ea = e0 + l31, eb = e0 + 32 + l31;
        #pragma unroll
        for (int r = 0; r < 16; ++r) {
            int i = (r & 3) + 8 * (r >> 2) + 4 * lhi;
            size_t row = bbase + g * 32 + i;
            float ga = bf2f(gatep[row * HID + ea]);
            float gb = bf2f(gatep[row * HID + eb]);
            attn_out[row * HID + ea] = f2bf(ga * o0[r]);
            attn_out[row * HID + eb] = f2bf(gb * o1[r]);
        }
    }
}

// ---------------- final LayerNorm ----------------
__global__ void k_ln(const float* __restrict__ h, const float* __restrict__ lng,
                     const float* __restrict__ lnb, float* __restrict__ out) {
    int bn = blockIdx.x;
    int t = threadIdx.x;
    const float4* r4 = (const float4*)(h + (size_t)bn * DIMD);
    float4 v = r4[t];
    float s  = v.x + v.y + v.z + v.w;
    float sq = v.x * v.x + v.y * v.y + v.z * v.z + v.w * v.w;
    __shared__ float red[4];
    #pragma unroll
    for (int o = 32; o; o >>= 1) { s += __shfl_down(s, o); sq += __shfl_down(sq, o); }
    int lane = t & 63, w = t >> 6;
    if (lane == 0) { red[w] = s; red[2 + w] = sq; }
    __syncthreads();
    float mu  = (red[0] + red[1]) * (1.0f / DIMD);
    float var = (red[2] + red[3]) * (1.0f / DIMD) - mu * mu;
    float rstd = 1.0f / sqrtf(var + EPSF);
    float4 gg = ((const float4*)lng)[t];
    float4 bb = ((const float4*)lnb)[t];
    float4 o;
    o.x = (v.x - mu) * rstd * gg.x + bb.x;
    o.y = (v.y - mu) * rstd * gg.y + bb.y;
    o.z = (v.z - mu) * rstd * gg.z + bb.z;
    o.w = (v.w - mu) * rstd * gg.w + bb.w;
    ((float4*)(out + (size_t)bn * DIMD))[t] = o;
}

extern "C" void kernel_launch(void* const* d_in, const int* in_sizes, int n_in,
                              void* d_out, int out_size, void* d_ws, size_t ws_size,
                              hipStream_t stream) {
    const int*   tokens = (const int*)d_in[0];
    const float* emb    = (const float*)d_in[1];
    const float* pos    = (const float*)d_in[2];
    const float* norm_g = (const float*)d_in[3];
    const float* Wh     = (const float*)d_in[4];
    const float* bh     = (const float*)d_in[5];
    const float* Wqk    = (const float*)d_in[6];
    const float* bqk    = (const float*)d_in[7];
    const float* gamma  = (const float*)d_in[8];
    const float* beta   = (const float*)d_in[9];
    const float* rp     = (const float*)d_in[10];
    const float* Wout   = (const float*)d_in[11];
    const float* bout   = (const float*)d_in[12];
    const float* lng    = (const float*)d_in[13];
    const float* lnb    = (const float*)d_in[14];

    float* h  = (float*)d_out;
    float* ws = (float*)d_ws;

    // ---- fixed allocations ----
    size_t off = 0;
    float* scale = ws + off; off += (size_t)BB * NIN;
    float* cosb  = ws + off; off += NIN * 16;
    float* sinb  = ws + off; off += NIN * 16;
    unsigned short* whqkT = (unsigned short*)(ws + off); off += (size_t)NLAYER * NFUSE * DIMD / 2;
    unsigned short* woutT = (unsigned short*)(ws + off); off += (size_t)NLAYER * DIMD * HID / 2;
    off = (off + 63) & ~(size_t)63;
    const size_t fixedFloats = off;

    // ---- size batch chunk ----
    const size_t wsFloats = ws_size / sizeof(float);
    // per batch (floats): nx bf16(256) + vT bf16(512) + gate bf16(512) + qk f32(128) + q4 bf16(256) + attn bf16(512)
    const size_t perBatch = (size_t)NIN * (DIMD / 2 + HID / 2 + HID / 2 + QKD + DIMD / 2 + HID / 2);
    int CB = BB;
    while (CB > 1 && fixedFloats + (size_t)CB * perBatch + 64 > wsFloats) CB >>= 1;

    unsigned short* nx    = (unsigned short*)(ws + off); off += (size_t)CB * NIN * DIMD / 2;
    unsigned short* vT    = (unsigned short*)(ws + off); off += (size_t)CB * HID * NIN / 2;
    unsigned short* gateB = (unsigned short*)(ws + off); off += (size_t)CB * NIN * HID / 2;
    float*          qk    = ws + off;                    off += (size_t)CB * NIN * QKD;
    unsigned short* q4    = (unsigned short*)(ws + off); off += (size_t)CB * NIN * DIMD / 2;
    unsigned short* attnB = (unsigned short*)(ws + off); off += (size_t)CB * NIN * HID / 2;

    const int BN_ = BB * NIN;

    k_cossin<<<8, 256, 0, stream>>>(cosb, sinb);
    k_embed<<<BN_, 128, 0, stream>>>(tokens, emb, pos, h);

    for (int l = 0; l < NLAYER; ++l) {
        unsigned short* whqkT_l = whqkT + (size_t)l * NFUSE * DIMD;
        k_wcast<<<(HID2 * DIMD / 8 + 255) / 256, 256, 0, stream>>>(
            Wh + (size_t)l * DIMD * HID2,  whqkT_l, DIMD, HID2);
        k_wcast<<<(QKD * DIMD / 8 + 255) / 256, 256, 0, stream>>>(
            Wqk + (size_t)l * DIMD * QKD,  whqkT_l + (size_t)HID2 * DIMD, DIMD, QKD);
        k_wcast<<<(DIMD * HID / 8 + 255) / 256, 256, 0, stream>>>(
            Wout + (size_t)l * HID * DIMD, woutT + (size_t)l * DIMD * HID, HID, DIMD);
    }

    for (int l = 0; l < NLAYER; ++l) {
        const float* bh_l  = bh   + (size_t)l * HID2;
        const float* bqk_l = bqk  + (size_t)l * QKD;
        const float* gm_l  = gamma+ (size_t)l * 4 * QKD;
        const float* bt_l  = beta + (size_t)l * 4 * QKD;
        const float* rp_l  = rp   + (size_t)l * 32;
        const float* bo_l  = bout + (size_t)l * DIMD;
        const unsigned short* whqkT_l = whqkT + (size_t)l * NFUSE * DIMD;
        const unsigned short* woutT_l = woutT + (size_t)l * DIMD * HID;

        for (int c0 = 0; c0 < BB; c0 += CB) {
            const int rowsC = CB * NIN;
            float* h_c = h + (size_t)c0 * NIN * DIMD;

            k_rms<<<rowsC / 4, 256, 0, stream>>>(h_c, scale, norm_g + l);
            k_nx<<<rowsC, 128, 0, stream>>>(h_c, scale, nx);

            dim3 g1(NFUSE / 128, rowsC / 128);
            k_gemm_bf16<0><<<g1, 256, 0, stream>>>(nx, whqkT_l, bh_l, bqk_l, nullptr,
                                                   qk, vT, gateB, rowsC, NFUSE, DIMD);

            k_rot<<<rowsC, 128, 0, stream>>>(qk, gm_l, bt_l, cosb, sinb, q4);

            dim3 ga(HID / 256, CB);
            k_attn2<<<ga, 256, 0, stream>>>(q4, gateB, vT, rp_l, attnB);

            dim3 g3(DIMD / 128, rowsC / 128);
            k_gemm_bf16<1><<<g3, 256, 0, stream>>>(attnB, woutT_l, bo_l, nullptr, h_c,
                                                   h_c, nullptr, nullptr, rowsC, DIMD, HID);
        }
    }

    k_ln<<<BN_, 128, 0, stream>>>(h, lng, lnb, (float*)d_out);
}

// Round 9
// 1429.310 us; speedup vs baseline: 5.3848x; 1.0653x over previous
//
#include <hip/hip_runtime.h>
#include <hip/hip_bf16.h>
#include <math.h>
#include <stdint.h>

#define BB   512
#define NIN  128
#define DIMD 512
#define QKD  128
#define GSZ  32
#define GRP  4
#define HID  1024
#define HID2 2048
#define NFUSE 2176   // HID2 + QKD
#define ROT  32
#define NLAYER 2
#define EPSF 1e-5f
#define BINS 100

typedef __bf16 bf16x8 __attribute__((ext_vector_type(8)));
typedef float  f32x4  __attribute__((ext_vector_type(4)));
typedef float  f32x16 __attribute__((ext_vector_type(16)));

__device__ __forceinline__ unsigned short f2bf(float f) {
    union { float f; uint32_t u; } v; v.f = f;
    return (unsigned short)((v.u + 0x7FFFu + ((v.u >> 16) & 1u)) >> 16);
}
__device__ __forceinline__ float bf2f(unsigned short h) {
    union { uint32_t u; float f; } v; v.u = ((uint32_t)h) << 16;
    return v.f;
}

// ---------------- embedding ----------------
__global__ void k_embed(const int* __restrict__ tokens, const float* __restrict__ emb,
                        const float* __restrict__ pos, float* __restrict__ h) {
    int bn = blockIdx.x;
    int n  = bn % NIN;
    int tok = tokens[bn];
    const float4* e4 = (const float4*)(emb + ((size_t)n * BINS + tok) * DIMD);
    const float4* p4 = (const float4*)(pos + (size_t)n * DIMD);
    float4* h4 = (float4*)(h + (size_t)bn * DIMD);
    int t = threadIdx.x;
    float4 a = e4[t], b = p4[t];
    h4[t] = make_float4(a.x + b.x, a.y + b.y, a.z + b.z, a.w + b.w);
}

// ---------------- RMS scale ----------------
__global__ void k_rms(const float* __restrict__ h, float* __restrict__ scale,
                      const float* __restrict__ ngp) {
    int row  = blockIdx.x * 4 + (threadIdx.x >> 6);
    int lane = threadIdx.x & 63;
    const float4* r4 = (const float4*)(h + (size_t)row * DIMD);
    float s = 0.f;
    #pragma unroll
    for (int i = 0; i < 2; ++i) {
        float4 v = r4[lane + 64 * i];
        s += v.x * v.x + v.y * v.y + v.z * v.z + v.w * v.w;
    }
    #pragma unroll
    for (int o = 32; o; o >>= 1) s += __shfl_down(s, o);
    if (lane == 0) {
        float nrm = sqrtf(s) * (1.0f / sqrtf((float)DIMD));
        scale[row] = ngp[0] / fmaxf(nrm, EPSF);
    }
}

// ---------------- build nx in bf16 (half-shifted) ----------------
__global__ void k_nx(const float* __restrict__ h, const float* __restrict__ scale,
                     unsigned short* __restrict__ nx) {
    int bn = blockIdx.x; int n = bn % NIN;
    int t = threadIdx.x;
    float4 v; float sc;
    if (t < 64) {
        if (n == 0) {
            ((ushort4*)(nx + (size_t)bn * DIMD))[t] = make_ushort4(0, 0, 0, 0);
            return;
        }
        sc = scale[bn - 1];
        v = ((const float4*)(h + (size_t)(bn - 1) * DIMD))[t];
    } else {
        sc = scale[bn];
        v = ((const float4*)(h + (size_t)bn * DIMD))[t];
    }
    ushort4 o = make_ushort4(f2bf(v.x * sc), f2bf(v.y * sc), f2bf(v.z * sc), f2bf(v.w * sc));
    ((ushort4*)(nx + (size_t)bn * DIMD))[t] = o;
}

// ---------------- weight cast+transpose: Wt[n][k] = bf16(W[k][n]) ----------------
__global__ void k_wcast(const float* __restrict__ W, unsigned short* __restrict__ Wt,
                        int K, int N) {
    int idx = blockIdx.x * 256 + threadIdx.x;
    int total = N * (K / 8);
    if (idx >= total) return;
    int kb = idx / N, n = idx % N;
    #pragma unroll
    for (int j = 0; j < 8; ++j)
        Wt[(size_t)n * K + kb * 8 + j] = f2bf(W[(size_t)(kb * 8 + j) * N + n]);
}

// ---------------- bf16 MFMA GEMM, BM=256 x BN=128, BK=32, dbuf prefetch ----------------
// MODE 0: fused Wh+Wqk — N=2176, silu; cols<1024 -> vT[b][e][n] bf16;
//         1024..2047 -> gate[row][e] bf16; >=2048 -> qk f32.
// MODE 1: Wout — N=512, no act, +resid, f32 C.
// T2 swizzle: LDS row = 32 bf16 = 4x16B slots; slot' = slot ^ (row & 3) on BOTH
// the pre-swizzled global source and the ds_read index (in-row involution).
#define GLOAD_LDS(gp, lp) __builtin_amdgcn_global_load_lds( \
    (const __attribute__((address_space(1))) uint32_t*)(gp), \
    (__attribute__((address_space(3))) uint32_t*)(lp), 16, 0, 0)

template<int MODE>
__global__ __launch_bounds__(256, 2) void k_gemm2(
        const unsigned short* __restrict__ A,
        const unsigned short* __restrict__ Bt,
        const float* __restrict__ bias0,
        const float* __restrict__ bias1,
        const float* __restrict__ resid,
        float* __restrict__ Cf,
        unsigned short* __restrict__ vTp,
        unsigned short* __restrict__ gatep,
        int M, int N, int K) {
    __shared__ unsigned short As[2][256 * 32];   // 2 x 16 KB
    __shared__ unsigned short Bs[2][128 * 32];   // 2 x 8 KB
    const int tid = threadIdx.x;

    // XCD-chunked bijective block swizzle (m204); nwg % 8 == 0 for our grids
    int flat = blockIdx.y * gridDim.x + blockIdx.x;
    int nwg  = gridDim.x * gridDim.y;
    int q = nwg >> 3, r = nwg & 7;
    int xcd = flat & 7, idx = flat >> 3;
    int swz = (xcd < r ? xcd * (q + 1) : r * (q + 1) + (xcd - r) * q) + idx;
    const int bxi = swz % gridDim.x, byi = swz / gridDim.x;
    const int bm = byi * 256, bn = bxi * 128;

    const int lane = tid & 63, wave = tid >> 6;   // wave w: rows [64w, 64w+64)
    const int l15 = lane & 15, l4 = lane >> 4;

    f32x4 acc[4][8];
    #pragma unroll
    for (int i = 0; i < 4; ++i)
        #pragma unroll
        for (int j = 0; j < 8; ++j) acc[i][j] = (f32x4){0.f, 0.f, 0.f, 0.f};

    // staging: thread -> (rowA = tid>>2, 16B slot tid&3); source slot pre-swizzled
    const int rowA = tid >> 2;                       // 0..63
    const int colO = (tid & 3) * 16;                 // linear LDS dest byte col
    const int colS = colO ^ ((rowA & 3) << 4);       // swizzled source byte col (in-row)
    const char* gA = (const char*)(A  + (size_t)(bm + rowA) * K) + colS;
    const char* gB = (const char*)(Bt + (size_t)(bn + rowA) * K) + colS;
    const size_t stride64 = (size_t)64 * K * 2;      // 64 rows in bytes
    unsigned short* dA0 = &As[0][tid * 8];
    unsigned short* dA1 = &As[1][tid * 8];
    unsigned short* dB0 = &Bs[0][tid * 8];
    unsigned short* dB1 = &Bs[1][tid * 8];

    #define STAGE2(dA, dB, k0) do { \
        const char* sA_ = gA + (size_t)(k0) * 2; \
        const char* sB_ = gB + (size_t)(k0) * 2; \
        GLOAD_LDS(sA_,                 (dA)); \
        GLOAD_LDS(sA_ +     stride64,  (dA) + 2048); \
        GLOAD_LDS(sA_ + 2 * stride64,  (dA) + 4096); \
        GLOAD_LDS(sA_ + 3 * stride64,  (dA) + 6144); \
        GLOAD_LDS(sB_,                 (dB)); \
        GLOAD_LDS(sB_ +     stride64,  (dB) + 2048); \
    } while (0)

    STAGE2(dA0, dB0, 0);
    asm volatile("s_waitcnt vmcnt(0)" ::: "memory");
    __syncthreads();

    const int NIT = K / 32;
    int bufc = 0;
    for (int it = 0; it < NIT; ++it) {
        if (it + 1 < NIT) {
            if (bufc == 0) STAGE2(dA1, dB1, (it + 1) * 32);
            else           STAGE2(dA0, dB0, (it + 1) * 32);
        }
        const unsigned short* Ab = As[bufc];
        const unsigned short* Bb = Bs[bufc];
        bf16x8 af[4], bfr[8];
        #pragma unroll
        for (int f = 0; f < 4; ++f) {
            int rA = wave * 64 + f * 16 + l15;
            af[f] = *(const bf16x8*)&Ab[rA * 32 + ((l4 ^ (rA & 3)) << 3)];
        }
        #pragma unroll
        for (int c = 0; c < 8; ++c) {
            int rB = c * 16 + l15;
            bfr[c] = *(const bf16x8*)&Bb[rB * 32 + ((l4 ^ (rB & 3)) << 3)];
        }
        #pragma unroll
        for (int f = 0; f < 4; ++f)
            #pragma unroll
            for (int c = 0; c < 8; ++c)
                acc[f][c] = __builtin_amdgcn_mfma_f32_16x16x32_bf16(af[f], bfr[c], acc[f][c], 0, 0, 0);
        asm volatile("s_waitcnt vmcnt(0)" ::: "memory");
        __syncthreads();
        bufc ^= 1;
    }
    #undef STAGE2

    #pragma unroll
    for (int f = 0; f < 4; ++f) {
        const int n0 = wave * 64 + f * 16 + l4 * 4;     // local row base (0..255)
        #pragma unroll
        for (int c = 0; c < 8; ++c) {
            const int col = bn + c * 16 + l15;
            if (MODE == 0) {
                float bsv = (col < 2 * HID) ? bias0[col] : bias1[col - 2 * HID];
                float vv[4];
                #pragma unroll
                for (int rr = 0; rr < 4; ++rr) {
                    float v = acc[f][c][rr] + bsv;
                    vv[rr] = v / (1.0f + __expf(-v));
                }
                if (col < HID) {
                    // vT[batch][e=col][n] ; tile spans 2 batches (n0>>7)
                    size_t batch = (size_t)byi * 2 + (n0 >> 7);
                    ushort4 o = make_ushort4(f2bf(vv[0]), f2bf(vv[1]), f2bf(vv[2]), f2bf(vv[3]));
                    *(ushort4*)&vTp[(batch * HID + col) * NIN + (n0 & 127)] = o;
                } else if (col < 2 * HID) {
                    #pragma unroll
                    for (int rr = 0; rr < 4; ++rr)
                        gatep[(size_t)(bm + n0 + rr) * HID + (col - HID)] = f2bf(vv[rr]);
                } else {
                    #pragma unroll
                    for (int rr = 0; rr < 4; ++rr)
                        Cf[(size_t)(bm + n0 + rr) * QKD + (col - 2 * HID)] = vv[rr];
                }
            } else {
                float bsv = bias0[col];
                #pragma unroll
                for (int rr = 0; rr < 4; ++rr) {
                    size_t row = bm + n0 + rr;
                    Cf[row * N + col] = acc[f][c][rr] + bsv + resid[row * N + col];
                }
            }
        }
    }
}

// ---------------- rotary cos/sin tables ----------------
__global__ void k_cossin(float* __restrict__ cosb, float* __restrict__ sinb) {
    int idx = blockIdx.x * 256 + threadIdx.x;
    if (idx >= NIN * 16) return;
    int n = idx / 16, i = idx % 16;
    double inv = pow(10000.0, -(double)(2 * i) / (double)ROT);
    double f = (double)n * inv;
    cosb[idx] = (float)cos(f);
    sinb[idx] = (float)sin(f);
}

// ---------------- qs = qk*gamma+beta (4 heads) + rotary, bf16 out ----------------
__global__ void k_rot(const float* __restrict__ qk, const float* __restrict__ gm,
                      const float* __restrict__ bt, const float* __restrict__ cosb,
                      const float* __restrict__ sinb, unsigned short* __restrict__ q4) {
    int bn = blockIdx.x; int n = bn % NIN;
    int d = threadIdx.x;   // 128
    float x = qk[(size_t)bn * QKD + d];
    float xp0 = 0.f;
    int dp = d ^ 1;
    if (d < ROT) xp0 = qk[(size_t)bn * QKD + dp];
    #pragma unroll
    for (int c = 0; c < 4; ++c) {
        float val = x * gm[c * QKD + d] + bt[c * QKD + d];
        float outv;
        if (d < ROT) {
            int i = d >> 1;
            float cs = cosb[n * 16 + i], sn = sinb[n * 16 + i];
            float xp = xp0 * gm[c * QKD + dp] + bt[c * QKD + dp];
            outv = ((d & 1) == 0) ? (val * cs - xp * sn) : (val * cs + xp * sn);
        } else outv = val;
        q4[((size_t)bn * 4 + c) * QKD + d] = f2bf(outv);
    }
}

// ---------------- MFMA fused attention ----------------
// grid (HID/256, CB); 256 threads = 4 waves; wave w owns e-cols [w*64, w*64+64).
__global__ __launch_bounds__(256) void k_attn2(
        const unsigned short* __restrict__ q4,    // [(b*128+n)*4 + c][128] bf16
        const unsigned short* __restrict__ gatep, // [b*128+n][1024] bf16
        const unsigned short* __restrict__ vT,    // [b][e][n] bf16
        const float* __restrict__ rp,
        unsigned short* __restrict__ attn_out) {  // [b*128+n][1024] bf16
    int et = blockIdx.x, b = blockIdx.y;
    int tid = threadIdx.x, wave = tid >> 6, lane = tid & 63;
    int l31 = lane & 31, lhi = lane >> 5;

    __shared__ unsigned short S[32][136];
    __shared__ float rps_d[32];
    if (tid < 32) {
        int d = tid, bucket;
        if (d < 16) bucket = d;
        else {
            bucket = 16 + (int)(logf((float)d * (1.0f / 16.0f)) * (16.0f / logf(8.0f)));
            if (bucket > 31) bucket = 31;
        }
        rps_d[tid] = rp[bucket] * sqrtf((float)QKD);
    }
    __syncthreads();

    size_t bbase = (size_t)b * NIN;
    int e0 = et * 256 + wave * 64;
    const unsigned short* vbase = vT + (size_t)b * HID * NIN;

    for (int g = 0; g < GRP; ++g) {
        if (wave <= g) {
            int gp = wave;
            bool quad = (gp == g);
            const unsigned short* Qb = q4 + ((bbase + g  * 32 + l31) * 4 + (quad ? 0 : 1)) * QKD;
            const unsigned short* Kb = q4 + ((bbase + gp * 32 + l31) * 4 + (quad ? 2 : 3)) * QKD;
            f32x16 sa = {};
            #pragma unroll
            for (int kk = 0; kk < 8; ++kk) {
                bf16x8 aq = *(const bf16x8*)(Qb + kk * 16 + lhi * 8);
                bf16x8 bk = *(const bf16x8*)(Kb + kk * 16 + lhi * 8);
                sa = __builtin_amdgcn_mfma_f32_32x32x16_bf16(aq, bk, sa, 0, 0, 0);
            }
            int j = l31;
            #pragma unroll
            for (int r = 0; r < 16; ++r) {
                int i = (r & 3) + 8 * (r >> 2) + 4 * lhi;
                float s = sa[r] * (1.0f / GSZ);
                if (quad) {
                    if (j > i) s = 0.f;
                    else {
                        s += rps_d[i - j];
                        s = fmaxf(s, 0.f);
                        s = s * s;
                    }
                }
                S[i][gp * 32 + j] = f2bf(s);
            }
        }
        __syncthreads();

        f32x16 o0 = {}, o1 = {};
        int KT = 2 * (g + 1);
        for (int kk = 0; kk < KT; ++kk) {
            int k0 = kk * 16 + lhi * 8;
            bf16x8 af = *(const bf16x8*)&S[l31][k0];
            bf16x8 b0 = *(const bf16x8*)(vbase + (size_t)(e0 + l31) * NIN + k0);
            bf16x8 b1 = *(const bf16x8*)(vbase + (size_t)(e0 + 32 + l31) * NIN + k0);
            o0 = __builtin_amdgcn_mfma_f32_32x32x16_bf16(af, b0, o0, 0, 0, 0);
            o1 = __builtin_amdgcn_mfma_f32_32x32x16_bf16(af, b1, o1, 0, 0, 0);
        }
        __syncthreads();

        int ea = e0 + l31, eb = e0 + 32 + l31;
        #pragma unroll
        for (int r = 0; r < 16; ++r) {
            int i = (r & 3) + 8 * (r >> 2) + 4 * lhi;
            size_t row = bbase + g * 32 + i;
            float ga = bf2f(gatep[row * HID + ea]);
            float gb = bf2f(gatep[row * HID + eb]);
            attn_out[row * HID + ea] = f2bf(ga * o0[r]);
            attn_out[row * HID + eb] = f2bf(gb * o1[r]);
        }
    }
}

// ---------------- final LayerNorm ----------------
__global__ void k_ln(const float* __restrict__ h, const float* __restrict__ lng,
                     const float* __restrict__ lnb, float* __restrict__ out) {
    int bn = blockIdx.x;
    int t = threadIdx.x;
    const float4* r4 = (const float4*)(h + (size_t)bn * DIMD);
    float4 v = r4[t];
    float s  = v.x + v.y + v.z + v.w;
    float sq = v.x * v.x + v.y * v.y + v.z * v.z + v.w * v.w;
    __shared__ float red[4];
    #pragma unroll
    for (int o = 32; o; o >>= 1) { s += __shfl_down(s, o); sq += __shfl_down(sq, o); }
    int lane = t & 63, w = t >> 6;
    if (lane == 0) { red[w] = s; red[2 + w] = sq; }
    __syncthreads();
    float mu  = (red[0] + red[1]) * (1.0f / DIMD);
    float var = (red[2] + red[3]) * (1.0f / DIMD) - mu * mu;
    float rstd = 1.0f / sqrtf(var + EPSF);
    float4 gg = ((const float4*)lng)[t];
    float4 bb = ((const float4*)lnb)[t];
    float4 o;
    o.x = (v.x - mu) * rstd * gg.x + bb.x;
    o.y = (v.y - mu) * rstd * gg.y + bb.y;
    o.z = (v.z - mu) * rstd * gg.z + bb.z;
    o.w = (v.w - mu) * rstd * gg.w + bb.w;
    ((float4*)(out + (size_t)bn * DIMD))[t] = o;
}

extern "C" void kernel_launch(void* const* d_in, const int* in_sizes, int n_in,
                              void* d_out, int out_size, void* d_ws, size_t ws_size,
                              hipStream_t stream) {
    const int*   tokens = (const int*)d_in[0];
    const float* emb    = (const float*)d_in[1];
    const float* pos    = (const float*)d_in[2];
    const float* norm_g = (const float*)d_in[3];
    const float* Wh     = (const float*)d_in[4];
    const float* bh     = (const float*)d_in[5];
    const float* Wqk    = (const float*)d_in[6];
    const float* bqk    = (const float*)d_in[7];
    const float* gamma  = (const float*)d_in[8];
    const float* beta   = (const float*)d_in[9];
    const float* rp     = (const float*)d_in[10];
    const float* Wout   = (const float*)d_in[11];
    const float* bout   = (const float*)d_in[12];
    const float* lng    = (const float*)d_in[13];
    const float* lnb    = (const float*)d_in[14];

    float* h  = (float*)d_out;
    float* ws = (float*)d_ws;

    // ---- fixed allocations ----
    size_t off = 0;
    float* scale = ws + off; off += (size_t)BB * NIN;
    float* cosb  = ws + off; off += NIN * 16;
    float* sinb  = ws + off; off += NIN * 16;
    unsigned short* whqkT = (unsigned short*)(ws + off); off += (size_t)NLAYER * NFUSE * DIMD / 2;
    unsigned short* woutT = (unsigned short*)(ws + off); off += (size_t)NLAYER * DIMD * HID / 2;
    off = (off + 63) & ~(size_t)63;
    const size_t fixedFloats = off;

    // ---- size batch chunk (keep CB >= 2 so M % 256 == 0) ----
    const size_t wsFloats = ws_size / sizeof(float);
    const size_t perBatch = (size_t)NIN * (DIMD / 2 + HID / 2 + HID / 2 + QKD + DIMD / 2 + HID / 2);
    int CB = BB;
    while (CB > 2 && fixedFloats + (size_t)CB * perBatch + 64 > wsFloats) CB >>= 1;

    unsigned short* nx    = (unsigned short*)(ws + off); off += (size_t)CB * NIN * DIMD / 2;
    unsigned short* vT    = (unsigned short*)(ws + off); off += (size_t)CB * HID * NIN / 2;
    unsigned short* gateB = (unsigned short*)(ws + off); off += (size_t)CB * NIN * HID / 2;
    float*          qk    = ws + off;                    off += (size_t)CB * NIN * QKD;
    unsigned short* q4    = (unsigned short*)(ws + off); off += (size_t)CB * NIN * DIMD / 2;
    unsigned short* attnB = (unsigned short*)(ws + off); off += (size_t)CB * NIN * HID / 2;

    const int BN_ = BB * NIN;

    k_cossin<<<8, 256, 0, stream>>>(cosb, sinb);
    k_embed<<<BN_, 128, 0, stream>>>(tokens, emb, pos, h);

    for (int l = 0; l < NLAYER; ++l) {
        unsigned short* whqkT_l = whqkT + (size_t)l * NFUSE * DIMD;
        k_wcast<<<(HID2 * DIMD / 8 + 255) / 256, 256, 0, stream>>>(
            Wh + (size_t)l * DIMD * HID2,  whqkT_l, DIMD, HID2);
        k_wcast<<<(QKD * DIMD / 8 + 255) / 256, 256, 0, stream>>>(
            Wqk + (size_t)l * DIMD * QKD,  whqkT_l + (size_t)HID2 * DIMD, DIMD, QKD);
        k_wcast<<<(DIMD * HID / 8 + 255) / 256, 256, 0, stream>>>(
            Wout + (size_t)l * HID * DIMD, woutT + (size_t)l * DIMD * HID, HID, DIMD);
    }

    for (int l = 0; l < NLAYER; ++l) {
        const float* bh_l  = bh   + (size_t)l * HID2;
        const float* bqk_l = bqk  + (size_t)l * QKD;
        const float* gm_l  = gamma+ (size_t)l * 4 * QKD;
        const float* bt_l  = beta + (size_t)l * 4 * QKD;
        const float* rp_l  = rp   + (size_t)l * 32;
        const float* bo_l  = bout + (size_t)l * DIMD;
        const unsigned short* whqkT_l = whqkT + (size_t)l * NFUSE * DIMD;
        const unsigned short* woutT_l = woutT + (size_t)l * DIMD * HID;

        for (int c0 = 0; c0 < BB; c0 += CB) {
            const int rowsC = CB * NIN;
            float* h_c = h + (size_t)c0 * NIN * DIMD;

            k_rms<<<rowsC / 4, 256, 0, stream>>>(h_c, scale, norm_g + l);
            k_nx<<<rowsC, 128, 0, stream>>>(h_c, scale, nx);

            dim3 g1(NFUSE / 128, rowsC / 256);
            k_gemm2<0><<<g1, 256, 0, stream>>>(nx, whqkT_l, bh_l, bqk_l, nullptr,
                                               qk, vT, gateB, rowsC, NFUSE, DIMD);

            k_rot<<<rowsC, 128, 0, stream>>>(qk, gm_l, bt_l, cosb, sinb, q4);

            dim3 ga(HID / 256, CB);
            k_attn2<<<ga, 256, 0, stream>>>(q4, gateB, vT, rp_l, attnB);

            dim3 g3(DIMD / 128, rowsC / 256);
            k_gemm2<1><<<g3, 256, 0, stream>>>(attnB, woutT_l, bo_l, nullptr, h_c,
                                               h_c, nullptr, nullptr, rowsC, DIMD, HID);
        }
    }

    k_ln<<<BN_, 128, 0, stream>>>(h, lng, lnb, (float*)d_out);
}